// Round 7
// baseline (248.892 us; speedup 1.0000x reference)
//
#include <hip/hip_runtime.h>
#include <stdint.h>

#define BN 4
#define SN 4096
#define EN 256
#define PN 32
#define FN 1024
#define BS (BN*SN)   // 16384
#define PAUG 64      // 32 xs chans + aug (+ zero pad to 64)

typedef uint16_t bf16_t;
typedef short v4s  __attribute__((ext_vector_type(4)));
typedef short v8s  __attribute__((ext_vector_type(8)));
typedef __bf16 bf16x8 __attribute__((ext_vector_type(8)));
typedef float v4f   __attribute__((ext_vector_type(4)));
typedef float v16f  __attribute__((ext_vector_type(16)));

#define MFMA16(a,b,c) __builtin_amdgcn_mfma_f32_16x16x32_bf16(a,b,c,0,0,0)
#define MFMA32(a,b,c) __builtin_amdgcn_mfma_f32_32x32x16_bf16(a,b,c,0,0,0)

__device__ __forceinline__ float b2f(bf16_t x){
    uint32_t u = ((uint32_t)x) << 16; float f; __builtin_memcpy(&f, &u, 4); return f;
}
__device__ __forceinline__ bf16_t f2b(float f){
    uint32_t u; __builtin_memcpy(&u, &f, 4);
    u += 0x7FFFu + ((u >> 16) & 1u);           // RNE
    return (bf16_t)(u >> 16);
}
__device__ __forceinline__ bf16x8 ldb8(const bf16_t* p){
    v8s r = *(const v8s*)p; return __builtin_bit_cast(bf16x8, r);
}
// 8-B-aligned load pair (for LDS rows with odd 8-B stride -> 2-way-free banks)
__device__ __forceinline__ bf16x8 ldb8u(const bf16_t* p){
    v4s lo = *(const v4s*)p;
    v4s hi = *(const v4s*)(p + 4);
    v8s r = __builtin_shufflevector(lo, hi, 0,1,2,3,4,5,6,7);
    return __builtin_bit_cast(bf16x8, r);
}
__device__ __forceinline__ float ldsc(const float* p){ return *p; }
__device__ __forceinline__ float ldsc(const bf16_t* p){ return b2f(*p); }
__device__ __forceinline__ void stsc(float* p, float v){ *p = v; }
__device__ __forceinline__ void stsc(bf16_t* p, float v){ *p = f2b(v); }

#if __has_builtin(__builtin_amdgcn_exp2f)
__device__ __forceinline__ float fexp2(float x){ return __builtin_amdgcn_exp2f(x); }
#else
__device__ __forceinline__ float fexp2(float x){ return exp2f(x); }
#endif

#if __has_builtin(__builtin_amdgcn_cvt_pk_bf16_f32)
typedef __bf16 bf16x2 __attribute__((ext_vector_type(2)));
__device__ __forceinline__ uint32_t pkbf16(float a, float b){
    bf16x2 r = __builtin_amdgcn_cvt_pk_bf16_f32(a, b);
    return __builtin_bit_cast(uint32_t, r);
}
#else
__device__ __forceinline__ uint32_t pkbf16(float a, float b){
    return (uint32_t)f2b(a) | ((uint32_t)f2b(b) << 16);
}
#endif

typedef const __attribute__((address_space(1))) uint32_t* glds_gp;
typedef __attribute__((address_space(3))) uint32_t* glds_lp;
__device__ __forceinline__ void glds16(const bf16_t* g, bf16_t* l){
    __builtin_amdgcn_global_load_lds((glds_gp)g, (glds_lp)l, 16, 0, 0);
}

// ---------------------------------------------------------------------------
// prep: (a) src fp32->bf16, (b) 4 weight cvts, (c) posxs. One launch.
// ---------------------------------------------------------------------------
__global__ __launch_bounds__(256) void prep_kernel(
    const float* __restrict__ src, bf16_t* __restrict__ srcb,
    const float* __restrict__ Wv, bf16_t* __restrict__ Wvb,
    const float* __restrict__ Wo, bf16_t* __restrict__ Wob,
    const float* __restrict__ W1, bf16_t* __restrict__ W1b,
    const float* __restrict__ W2, bf16_t* __restrict__ W2b,
    const float* __restrict__ pos, const float* __restrict__ Wp,
    const float* __restrict__ bp,  const float* __restrict__ lsp,
    bf16_t* __restrict__ xk, bf16_t* __restrict__ xq)
{
    __shared__ float Wsh[PN*PN];
    __shared__ float bsh[PN];
    int bid = blockIdx.x;
    int tid = threadIdx.x;

    if (bid < 4736){
        const float* sp; bf16_t* dp; int off;
        if (bid < 4096){ sp = src; dp = srcb; off = (bid*256 + tid)*4; }
        else {
            int i = ((bid - 4096)*256 + tid)*4;
            if      (i <  65536){ sp=Wv; dp=Wvb; off=i; }
            else if (i < 131072){ sp=Wo; dp=Wob; off=i- 65536; }
            else if (i < 393216){ sp=W1; dp=W1b; off=i-131072; }
            else                { sp=W2; dp=W2b; off=i-393216; }
        }
        float4 f = *(const float4*)(sp + off);
        v4s o;
        o.x = (short)f2b(f.x); o.y = (short)f2b(f.y);
        o.z = (short)f2b(f.z); o.w = (short)f2b(f.w);
        *(v4s*)(dp + off) = o;
        return;
    }

    int pb = bid - 4736;          // 0..63
    int b  = pb >> 4;
    int s  = (pb & 15)*256 + tid;

    for (int i = tid; i < PN*PN; i += 256) Wsh[i] = Wp[i];
    if (tid < PN) bsh[tid] = bp[tid];
    __syncthreads();

    float inv_ls = 1.0f / lsp[0];
    const float c1f = 1.4426950408889634f;

    float col[PN];
    #pragma unroll
    for (int p = 0; p < PN; p++) col[p] = pos[((size_t)b*PN + p)*SN + s];

    uint16_t xb[PN], qb[PN];
    float sq = 0.f;
    #pragma unroll 4
    for (int o = 0; o < PN; o++){
        float pe = bsh[o];
        #pragma unroll
        for (int p = 0; p < PN; p++) pe += col[p] * Wsh[o*PN + p];
        float pv = pe * inv_ls;
        uint16_t h = f2b(pv);
        xb[o] = h;
        qb[o] = f2b(c1f * pv);
        float xr = b2f(h);
        sq += xr * xr;
    }

    size_t base = ((size_t)b*SN + s) * PAUG;
    v8s pk[8];
    #pragma unroll
    for (int c = 0; c < 4; c++)
        #pragma unroll
        for (int j = 0; j < 8; j++) ((short*)&pk[c])[j] = (short)xb[c*8 + j];
    #pragma unroll
    for (int c = 4; c < 8; c++)
        #pragma unroll
        for (int j = 0; j < 8; j++) ((short*)&pk[c])[j] = 0;
    ((short*)&pk[4])[0] = (short)f2b(-0.5f * sq);
    ((short*)&pk[4])[1] = (short)0x3F80;   // 1.0
    #pragma unroll
    for (int c = 0; c < 8; c++) *(v8s*)(xk + base + c*8) = pk[c];

    #pragma unroll
    for (int c = 0; c < 4; c++)
        #pragma unroll
        for (int j = 0; j < 8; j++) ((short*)&pk[c])[j] = (short)qb[c*8 + j];
    ((short*)&pk[4])[0] = (short)f2b(c1f);
    ((short*)&pk[4])[1] = (short)f2b(-0.5f * sq * c1f);
    #pragma unroll
    for (int c = 0; c < 8; c++) *(v8s*)(xq + base + c*8) = pk[c];
}

// ---------------------------------------------------------------------------
// gemm_t (64x64 tile) -- kept ONLY for the Wv projection (EPI 3: fragment-
// ordered V store for attn). See gemm128 for the big GEMMs.
// ---------------------------------------------------------------------------
template<int EPI, typename OutT>
__global__ __launch_bounds__(256) void gemm_t(
    const bf16_t* __restrict__ A, const bf16_t* __restrict__ W,
    const float* __restrict__ bias, OutT* __restrict__ out,
    bf16_t* __restrict__ vt, int N, int K)
{
    __shared__ __align__(16) bf16_t At[2][4096];   // 2 x 8 KB
    __shared__ __align__(16) bf16_t Wt[2][4096];   // 2 x 8 KB
    int tid = threadIdx.x;
    int lane = tid & 63, wv = tid >> 6, col = lane & 15, quad = lane >> 4;
    int m0 = blockIdx.x * 64, n0 = blockIdx.y * 64;
    int nck = K >> 6;

    int srow = tid >> 3;                      // 0..31
    int spc  = (tid & 7) ^ (srow & 7);        // swizzled source piece
    const bf16_t* asrc = A + (size_t)(m0 + srow)*K + spc*8;
    const bf16_t* wsrc = W + (size_t)(n0 + srow)*K + spc*8;

    v4f acc[4];
    #pragma unroll
    for (int t = 0; t < 4; t++) acc[t] = (v4f){0.f,0.f,0.f,0.f};

    // stage chunk 0
    glds16(asrc, &At[0][tid*8]);
    glds16(asrc + (size_t)32*K, &At[0][2048 + tid*8]);
    glds16(wsrc, &Wt[0][tid*8]);
    glds16(wsrc + (size_t)32*K, &Wt[0][2048 + tid*8]);
    __syncthreads();

    for (int c = 0; c < nck; c++){
        int cb = c & 1;
        if (c + 1 < nck){
            glds16(asrc + (c+1)*64, &At[cb^1][tid*8]);
            glds16(asrc + (size_t)32*K + (c+1)*64, &At[cb^1][2048 + tid*8]);
            glds16(wsrc + (c+1)*64, &Wt[cb^1][tid*8]);
            glds16(wsrc + (size_t)32*K + (c+1)*64, &Wt[cb^1][2048 + tid*8]);
        }
        #pragma unroll
        for (int kc = 0; kc < 2; kc++){
            int pc = ((kc*4 + quad) ^ (col & 7)) * 8;
            bf16x8 a = ldb8(&At[cb][(wv*16 + col)*64 + pc]);
            #pragma unroll
            for (int t = 0; t < 4; t++){
                bf16x8 b = ldb8(&Wt[cb][(t*16 + col)*64 + pc]);
                acc[t] = MFMA16(a, b, acc[t]);
            }
        }
        __syncthreads();
    }

    float bfv[4];
    #pragma unroll
    for (int t = 0; t < 4; t++) bfv[t] = bias[n0 + t*16 + col];

    if constexpr (EPI == 3){
        __shared__ uint16_t Tsh[64*74];
        #pragma unroll
        for (int r = 0; r < 4; r++)
            #pragma unroll
            for (int t = 0; t < 4; t++)
                Tsh[(wv*16 + quad*4 + r)*74 + t*16 + col] = f2b(acc[t][r] + bfv[t]);
        __syncthreads();
        int e = tid >> 2, sc = tid & 3;
        int b = m0 >> 12;
        int sbat = m0 & (SN-1);
        int eb   = (n0 + e) >> 5;
        int l31e = (n0 + e) & 31;
        int k16  = (sbat >> 4) + sc;
        v8s p0, p1;
        #pragma unroll
        for (int i = 0; i < 8; i++) ((short*)&p0)[i] = (short)Tsh[(sc*16 + i)*74 + e];
        #pragma unroll
        for (int i = 0; i < 8; i++) ((short*)&p1)[i] = (short)Tsh[(sc*16 + 8 + i)*74 + e];
        bf16_t* dst = vt + ((((size_t)b*8 + eb)*256 + k16)*64 + l31e)*8;
        *(v8s*)dst = p0;              // half 0 (keys s&15 in 0..7)
        *(v8s*)(dst + 256) = p1;      // half 1 (keys s&15 in 8..15), +32 lanes
    } else {
        #pragma unroll
        for (int r = 0; r < 4; r++){
            int row = m0 + wv*16 + quad*4 + r;
            #pragma unroll
            for (int t = 0; t < 4; t++){
                float y = acc[t][r] + bfv[t];
                if constexpr (EPI == 1) y = fmaxf(y, 0.f);
                stsc(out + (size_t)row*N + n0 + t*16 + col, y);
            }
        }
    }
}

// ---------------------------------------------------------------------------
// gemm128: out = A @ W^T + bias (opt relu). 128m x 128n tile, 256 thr.
// Wave wv owns m-strip [wv*32, wv*32+32) x all 128 n: acc[2][8] v4f.
// BK=64, double-buffered (64 KB LDS), global_load_lds 16B staging with the
// proven source-side XOR piece-swizzle (linear LDS dest, 128 B rows, all
// b128 fragment reads 2-way-free). MFMA16:ds_read = 32:20 per chunk (vs
// 16:16 in gemm_t) -> ~2.6x the 64-tile throughput class (m92->m93 ladder).
// EPI 0: bias ; 1: bias+relu.
// ---------------------------------------------------------------------------
template<int EPI>
__global__ __launch_bounds__(256, 2) void gemm128(
    const bf16_t* __restrict__ A, const bf16_t* __restrict__ W,
    const float* __restrict__ bias, bf16_t* __restrict__ out,
    int N, int K)
{
    __shared__ __align__(16) bf16_t At[2][8192];   // 2 x 16 KB (128 rows x 64)
    __shared__ __align__(16) bf16_t Wt[2][8192];   // 2 x 16 KB
    int tid = threadIdx.x;
    int lane = tid & 63, wv = tid >> 6, col = lane & 15, quad = lane >> 4;
    int m0 = blockIdx.x * 128, n0 = blockIdx.y * 128;
    int nck = K >> 6;

    int srow = tid >> 3;                      // 0..31
    int spc  = (tid & 7) ^ (srow & 7);        // swizzled source piece
    const bf16_t* asrc = A + (size_t)(m0 + srow)*K + spc*8;
    const bf16_t* wsrc = W + (size_t)(n0 + srow)*K + spc*8;

    v4f acc[2][8];
    #pragma unroll
    for (int mi = 0; mi < 2; mi++)
        #pragma unroll
        for (int t = 0; t < 8; t++) acc[mi][t] = (v4f){0.f,0.f,0.f,0.f};

    // stage chunk 0: 4 row-groups of 32 per matrix
    #pragma unroll
    for (int s = 0; s < 4; s++){
        glds16(asrc + (size_t)(s*32)*K, &At[0][s*2048 + tid*8]);
        glds16(wsrc + (size_t)(s*32)*K, &Wt[0][s*2048 + tid*8]);
    }
    __syncthreads();

    for (int c = 0; c < nck; c++){
        int cb = c & 1;
        if (c + 1 < nck){
            #pragma unroll
            for (int s = 0; s < 4; s++){
                glds16(asrc + (size_t)(s*32)*K + (c+1)*64, &At[cb^1][s*2048 + tid*8]);
                glds16(wsrc + (size_t)(s*32)*K + (c+1)*64, &Wt[cb^1][s*2048 + tid*8]);
            }
        }
        #pragma unroll
        for (int kc = 0; kc < 2; kc++){
            int pc = ((kc*4 + quad) ^ (col & 7)) * 8;
            bf16x8 a[2];
            #pragma unroll
            for (int mi = 0; mi < 2; mi++)
                a[mi] = ldb8(&At[cb][(wv*32 + mi*16 + col)*64 + pc]);
            #pragma unroll
            for (int t = 0; t < 8; t++){
                bf16x8 b = ldb8(&Wt[cb][(t*16 + col)*64 + pc]);
                #pragma unroll
                for (int mi = 0; mi < 2; mi++)
                    acc[mi][t] = MFMA16(a[mi], b, acc[mi][t]);
            }
        }
        __syncthreads();
    }

    float bfv[8];
    #pragma unroll
    for (int t = 0; t < 8; t++) bfv[t] = bias[n0 + t*16 + col];

    #pragma unroll
    for (int mi = 0; mi < 2; mi++){
        #pragma unroll
        for (int r = 0; r < 4; r++){
            int row = m0 + wv*32 + mi*16 + quad*4 + r;
            #pragma unroll
            for (int t = 0; t < 8; t++){
                float y = acc[mi][t][r] + bfv[t];
                if constexpr (EPI == 1) y = fmaxf(y, 0.f);
                out[(size_t)row*N + n0 + t*16 + col] = f2b(y);
            }
        }
    }
}

// ---------------------------------------------------------------------------
// ln_kernel: out = LayerNorm(y + res) * gamma + beta.  32 rows/block.
// ---------------------------------------------------------------------------
template<typename OutT, typename ResT>
__global__ __launch_bounds__(256) void ln_kernel(
    const bf16_t* __restrict__ y, const ResT* __restrict__ res,
    const float* __restrict__ gamma, const float* __restrict__ beta,
    OutT* __restrict__ out)
{
    int tid = threadIdx.x;
    int row = blockIdx.x * 32 + (tid >> 3);
    int l8  = tid & 7;
    size_t base = (size_t)row * EN;
    float v[32];
    float s1 = 0.f, s2 = 0.f;
    #pragma unroll
    for (int i = 0; i < 4; i++){
        int off = l8*8 + i*64;
        v8s a = *(const v8s*)(y + base + off);
        #pragma unroll
        for (int j = 0; j < 8; j++){
            float t = b2f((bf16_t)(uint16_t)a[j]) + ldsc(res + base + off + j);
            v[i*8 + j] = t; s1 += t; s2 += t*t;
        }
    }
    #pragma unroll
    for (int m = 1; m <= 4; m <<= 1){
        s1 += __shfl_xor(s1, m);
        s2 += __shfl_xor(s2, m);
    }
    float mu = s1 * (1.f/256.f);
    float rs = rsqrtf(s2 * (1.f/256.f) - mu*mu + 1e-5f);
    #pragma unroll
    for (int i = 0; i < 4; i++){
        int off = l8*8 + i*64;
        #pragma unroll
        for (int j = 0; j < 8; j++)
            stsc(out + base + off + j, (v[i*8+j]-mu)*rs*gamma[off+j] + beta[off+j]);
    }
}

// ---------------------------------------------------------------------------
// Attention (round-6 structure, unchanged): Q=64/block, grid 256, 512 thr.
// Chunk=128 keys, vfrag-in-regs PV, raw barrier (no vmcnt drain), Wtb parity
// double-buffer, kf prefetch.
// ---------------------------------------------------------------------------
__global__ __launch_bounds__(512, 4) void attn_kernel(
    const bf16_t* __restrict__ xk, const bf16_t* __restrict__ xq,
    const bf16_t* __restrict__ vf, const float* __restrict__ osp,
    bf16_t* __restrict__ ctx)
{
    __shared__ __align__(16) bf16_t Wtb[2][64*132];   // 33 KB
    __shared__ __align__(16) bf16_t Qs[64*64];        // 8 KB
    __shared__ float densh[8][64];                    // 2 KB
    __shared__ float dent[64];

    int tid  = threadIdx.x;
    int lane = tid & 63;
    int wv   = tid >> 6;          // 0..7
    int col  = lane & 15;
    int quad = lane >> 4;
    int l31  = lane & 31;
    int half = lane >> 5;

    // batch b pinned to XCD pair {2b,2b+1} -> its V slice L2-resident
    int bid = blockIdx.x;                    // 0..255
    int b   = (bid & 7) >> 1;
    int qi  = ((bid >> 3) << 1) | (bid & 1); // 0..63
    int q0  = qi * 64;

    float k2 = 1.4426950408889634f * osp[0];

    const bf16_t* xkb = xk + (size_t)b * SN * PAUG;
    const bf16_t* xqb = xq + (size_t)b * SN * PAUG;
    // this wave's V-fragment stream: [k16 = 0..255][lane][8]
    const bf16_t* vfb = vf + (((size_t)b*8 + wv)*256)*512 + lane*8;

    // stage Q tile: 512 thr x 16 B = 8 KB, piece-swizzled SOURCE, linear dest
    {
        int qrow = tid >> 3;                 // 0..63
        int qpc  = (tid & 7) ^ (qrow & 7);
        glds16(xqb + (size_t)(q0 + qrow)*PAUG + qpc*8, &Qs[tid*8]);
    }

    v16f acc[2];
    #pragma unroll
    for (int qg = 0; qg < 2; qg++)
        #pragma unroll
        for (int i = 0; i < 16; i++) acc[qg][i] = 0.f;
    float den[4] = {0.f, 0.f, 0.f, 0.f};     // [qg*2+g2]
    const v4f zero = (v4f){0.f,0.f,0.f,0.f};

    // kf prologue (chunk 0): this wave's 16 keys, 2 paug-halves
    bf16x8 kf0, kf1;
    {
        const bf16_t* kr = xkb + (size_t)(wv*16 + col)*PAUG + quad*8;
        kf0 = ldb8(kr); kf1 = ldb8(kr + 32);
    }

    __syncthreads();   // Qs staged (one-time full drain)

    for (int c = 0; c < 32; c++){
        int cb = c & 1;
        // issue V(c): 8 coalesced b128 into regs (QK covers L2 latency)
        bf16x8 vr[8];
        #pragma unroll
        for (int sk = 0; sk < 8; sk++)
            vr[sk] = ldb8(vfb + (size_t)(c*8 + sk)*512);

        // QK + exp: this wave's 16-key slice x 64 q of chunk c
        #pragma unroll
        for (int qg = 0; qg < 2; qg++){
            #pragma unroll
            for (int g2 = 0; g2 < 2; g2++){
                int qr = qg*32 + g2*16 + col;
                bf16x8 qa = ldb8(&Qs[qr*64 + ((quad    ) ^ (col & 7))*8]);
                bf16x8 qb = ldb8(&Qs[qr*64 + ((4 + quad) ^ (col & 7))*8]);
                v4f st = MFMA16(kf0, qa, zero);
                st = MFMA16(kf1, qb, st);
                #pragma unroll
                for (int rp = 0; rp < 2; rp++){
                    float w0 = fexp2(fmaf(k2, fexp2(st[rp*2+0]), -k2));
                    float w1 = fexp2(fmaf(k2, fexp2(st[rp*2+1]), -k2));
                    den[qg*2+g2] += w0 + w1;
                    *(uint32_t*)&Wtb[cb][qr*132 + wv*16 + quad*4 + rp*2]
                        = pkbf16(w0, w1);
                }
            }
        }

        // prefetch kf(c+1) (global load, stays in flight across raw barrier)
        if (c + 1 < 32){
            const bf16_t* kr = xkb + (size_t)((c+1)*128 + wv*16 + col)*PAUG + quad*8;
            kf0 = ldb8(kr); kf1 = ldb8(kr + 32);
        }

        // LDS-visibility barrier WITHOUT vmcnt drain
        asm volatile("s_waitcnt lgkmcnt(0)" ::: "memory");
        __builtin_amdgcn_s_barrier();
        __builtin_amdgcn_sched_barrier(0);

        // PV chunk c: this wave's 32-e slice, 2 qg x 8 MFMA32 over k=128
        #pragma unroll
        for (int qg = 0; qg < 2; qg++){
            #pragma unroll
            for (int sk4 = 0; sk4 < 2; sk4++){
                bf16x8 af[4];
                #pragma unroll
                for (int j = 0; j < 4; j++)
                    af[j] = ldb8u(&Wtb[cb][(qg*32 + l31)*132 + (sk4*4 + j)*16 + half*8]);
                #pragma unroll
                for (int j = 0; j < 4; j++)
                    acc[qg] = MFMA32(af[j], vr[sk4*4 + j], acc[qg]);
            }
        }
    }

    #pragma unroll
    for (int d = 0; d < 4; d++){
        den[d] += __shfl_xor(den[d], 16);
        den[d] += __shfl_xor(den[d], 32);
    }
    if (lane < 16){
        #pragma unroll
        for (int qg = 0; qg < 2; qg++)
            #pragma unroll
            for (int g2 = 0; g2 < 2; g2++)
                densh[wv][qg*32 + g2*16 + lane] = den[qg*2+g2];
    }
    __syncthreads();
    if (tid < 64){
        float s = 0.f;
        #pragma unroll
        for (int w = 0; w < 8; w++) s += densh[w][tid];
        dent[tid] = 1.f / s;
    }
    __syncthreads();

    size_t obase = ((size_t)b*SN + q0) * EN + wv*32;
    #pragma unroll
    for (int qg = 0; qg < 2; qg++){
        #pragma unroll
        for (int rg = 0; rg < 16; rg++){
            int row = (rg & 3) + 8*(rg >> 2) + 4*half;
            float inv = dent[qg*32 + row];
            ctx[obase + (size_t)(qg*32 + row)*EN + l31] = f2b(acc[qg][rg] * inv);
        }
    }
}

// ---------------------------------------------------------------------------
extern "C" void kernel_launch(void* const* d_in, const int* in_sizes, int n_in,
                              void* d_out, int out_size, void* d_ws, size_t ws_size,
                              hipStream_t stream)
{
    (void)in_sizes; (void)n_in; (void)out_size; (void)ws_size;
    const float* src  = (const float*)d_in[0];
    const float* pos  = (const float*)d_in[1];
    const float* Wpos = (const float*)d_in[2];
    const float* bpos = (const float*)d_in[3];
    const float* ls   = (const float*)d_in[4];
    const float* os   = (const float*)d_in[5];
    const float* Wv   = (const float*)d_in[6];
    const float* bv   = (const float*)d_in[7];
    const float* Wo   = (const float*)d_in[8];
    const float* bo   = (const float*)d_in[9];
    const float* W1   = (const float*)d_in[10];
    const float* b1   = (const float*)d_in[11];
    const float* W2   = (const float*)d_in[12];
    const float* b2   = (const float*)d_in[13];
    const float* g1   = (const float*)d_in[14];
    const float* be1  = (const float*)d_in[15];
    const float* g2   = (const float*)d_in[16];
    const float* be2  = (const float*)d_in[17];

    char* w = (char*)d_ws;
    bf16_t* xkb  = (bf16_t*)(w);                         // 2 MB [B,S,64]
    bf16_t* xqb  = (bf16_t*)(w + ( 2u<<20));             // 2 MB
    bf16_t* Wvb  = (bf16_t*)(w + ( 4u<<20));             // 128 KB
    bf16_t* Wob  = (bf16_t*)(w + ( 4u<<20) + (1u<<18));  // 128 KB
    bf16_t* W1b  = (bf16_t*)(w + ( 5u<<20));             // 512 KB
    bf16_t* W2b  = (bf16_t*)(w + ( 6u<<20));             // 512 KB
    bf16_t* srcb = (bf16_t*)(w + ( 8u<<20));             // 8 MB (alive thru ln1)
    bf16_t* y2   = (bf16_t*)(w + ( 8u<<20));             // aliases srcb (after ln1)
    bf16_t* vtg  = (bf16_t*)(w + (16u<<20));             // 8 MB vfrag (dead after attn)
    bf16_t* y1   = (bf16_t*)(w + (16u<<20));             // aliases vtg
    bf16_t* ctx  = (bf16_t*)(w + (24u<<20));             // 8 MB (dead after Wo-gemm)
    bf16_t* xws  = (bf16_t*)(w + (24u<<20));             // aliases ctx (after Wo-gemm)
    bf16_t* hws  = (bf16_t*)(w + (32u<<20));             // 32 MB

    prep_kernel<<<dim3(4800), 256, 0, stream>>>(
        src, srcb, Wv, Wvb, Wo, Wob, W1, W1b, W2, W2b,
        pos, Wpos, bpos, ls, xkb, xqb);

    // v = src @ Wv^T + bv  -> fragment-ordered store vfrag[b][eb][k16][lane][8]
    gemm_t<3, bf16_t><<<dim3(BS/64, EN/64), 256, 0, stream>>>(
        srcb, Wvb, bv, (bf16_t*)nullptr, vtg, EN, EN);
    // ctx = softmax(os*exp(-0.5*d2)) @ v
    attn_kernel<<<dim3(256), 512, 0, stream>>>(xkb, xqb, vtg, os, ctx);
    // y1 = ctx @ Wo^T + bo ; x = LN1(y1 + src)
    gemm128<0><<<dim3(BS/128, EN/128), 256, 0, stream>>>(
        ctx, Wob, bo, y1, EN, EN);
    ln_kernel<bf16_t, bf16_t><<<dim3(BS/32), 256, 0, stream>>>(y1, srcb, g1, be1, xws);
    // h = relu(x @ W1^T + b1)
    gemm128<1><<<dim3(BS/128, FN/128), 256, 0, stream>>>(
        xws, W1b, b1, hws, FN, EN);
    // y2 = h @ W2^T + b2 ; out = LN2(y2 + x) -> fp32
    gemm128<0><<<dim3(BS/128, EN/128), 256, 0, stream>>>(
        hws, W2b, b2, y2, EN, FN);
    ln_kernel<float, bf16_t><<<dim3(BS/32), 256, 0, stream>>>(y2, xws, g2, be2, (float*)d_out);
}

// Round 8
// 232.522 us; speedup vs baseline: 1.0704x; 1.0704x over previous
//
#include <hip/hip_runtime.h>
#include <stdint.h>

#define BN 4
#define SN 4096
#define EN 256
#define PN 32
#define FN 1024
#define BS (BN*SN)   // 16384
#define PAUG 64      // 32 xs chans + aug (+ zero pad to 64)

typedef uint16_t bf16_t;
typedef short v4s  __attribute__((ext_vector_type(4)));
typedef short v8s  __attribute__((ext_vector_type(8)));
typedef __bf16 bf16x8 __attribute__((ext_vector_type(8)));
typedef float v4f   __attribute__((ext_vector_type(4)));
typedef float v16f  __attribute__((ext_vector_type(16)));

#define MFMA16(a,b,c) __builtin_amdgcn_mfma_f32_16x16x32_bf16(a,b,c,0,0,0)
#define MFMA32(a,b,c) __builtin_amdgcn_mfma_f32_32x32x16_bf16(a,b,c,0,0,0)

__device__ __forceinline__ float b2f(bf16_t x){
    uint32_t u = ((uint32_t)x) << 16; float f; __builtin_memcpy(&f, &u, 4); return f;
}
__device__ __forceinline__ bf16_t f2b(float f){
    uint32_t u; __builtin_memcpy(&u, &f, 4);
    u += 0x7FFFu + ((u >> 16) & 1u);           // RNE
    return (bf16_t)(u >> 16);
}
__device__ __forceinline__ bf16x8 ldb8(const bf16_t* p){
    v8s r = *(const v8s*)p; return __builtin_bit_cast(bf16x8, r);
}
// 8-B-aligned load pair (for LDS rows with odd 8-B stride -> 2-way-free banks)
__device__ __forceinline__ bf16x8 ldb8u(const bf16_t* p){
    v4s lo = *(const v4s*)p;
    v4s hi = *(const v4s*)(p + 4);
    v8s r = __builtin_shufflevector(lo, hi, 0,1,2,3,4,5,6,7);
    return __builtin_bit_cast(bf16x8, r);
}
__device__ __forceinline__ float ldsc(const float* p){ return *p; }
__device__ __forceinline__ float ldsc(const bf16_t* p){ return b2f(*p); }
__device__ __forceinline__ void stsc(float* p, float v){ *p = v; }
__device__ __forceinline__ void stsc(bf16_t* p, float v){ *p = f2b(v); }

#if __has_builtin(__builtin_amdgcn_exp2f)
__device__ __forceinline__ float fexp2(float x){ return __builtin_amdgcn_exp2f(x); }
#else
__device__ __forceinline__ float fexp2(float x){ return exp2f(x); }
#endif

#if __has_builtin(__builtin_amdgcn_cvt_pk_bf16_f32)
typedef __bf16 bf16x2 __attribute__((ext_vector_type(2)));
__device__ __forceinline__ uint32_t pkbf16(float a, float b){
    bf16x2 r = __builtin_amdgcn_cvt_pk_bf16_f32(a, b);
    return __builtin_bit_cast(uint32_t, r);
}
#else
__device__ __forceinline__ uint32_t pkbf16(float a, float b){
    return (uint32_t)f2b(a) | ((uint32_t)f2b(b) << 16);
}
#endif

typedef const __attribute__((address_space(1))) uint32_t* glds_gp;
typedef __attribute__((address_space(3))) uint32_t* glds_lp;
__device__ __forceinline__ void glds16(const bf16_t* g, bf16_t* l){
    __builtin_amdgcn_global_load_lds((glds_gp)g, (glds_lp)l, 16, 0, 0);
}

// ---------------------------------------------------------------------------
// prep: (a) src fp32->bf16, (b) 4 weight cvts, (c) posxs. One launch.
// ---------------------------------------------------------------------------
__global__ __launch_bounds__(256) void prep_kernel(
    const float* __restrict__ src, bf16_t* __restrict__ srcb,
    const float* __restrict__ Wv, bf16_t* __restrict__ Wvb,
    const float* __restrict__ Wo, bf16_t* __restrict__ Wob,
    const float* __restrict__ W1, bf16_t* __restrict__ W1b,
    const float* __restrict__ W2, bf16_t* __restrict__ W2b,
    const float* __restrict__ pos, const float* __restrict__ Wp,
    const float* __restrict__ bp,  const float* __restrict__ lsp,
    bf16_t* __restrict__ xk, bf16_t* __restrict__ xq)
{
    __shared__ float Wsh[PN*PN];
    __shared__ float bsh[PN];
    int bid = blockIdx.x;
    int tid = threadIdx.x;

    if (bid < 4736){
        const float* sp; bf16_t* dp; int off;
        if (bid < 4096){ sp = src; dp = srcb; off = (bid*256 + tid)*4; }
        else {
            int i = ((bid - 4096)*256 + tid)*4;
            if      (i <  65536){ sp=Wv; dp=Wvb; off=i; }
            else if (i < 131072){ sp=Wo; dp=Wob; off=i- 65536; }
            else if (i < 393216){ sp=W1; dp=W1b; off=i-131072; }
            else                { sp=W2; dp=W2b; off=i-393216; }
        }
        float4 f = *(const float4*)(sp + off);
        v4s o;
        o.x = (short)f2b(f.x); o.y = (short)f2b(f.y);
        o.z = (short)f2b(f.z); o.w = (short)f2b(f.w);
        *(v4s*)(dp + off) = o;
        return;
    }

    int pb = bid - 4736;          // 0..63
    int b  = pb >> 4;
    int s  = (pb & 15)*256 + tid;

    for (int i = tid; i < PN*PN; i += 256) Wsh[i] = Wp[i];
    if (tid < PN) bsh[tid] = bp[tid];
    __syncthreads();

    float inv_ls = 1.0f / lsp[0];
    const float c1f = 1.4426950408889634f;

    float col[PN];
    #pragma unroll
    for (int p = 0; p < PN; p++) col[p] = pos[((size_t)b*PN + p)*SN + s];

    uint16_t xb[PN], qb[PN];
    float sq = 0.f;
    #pragma unroll 4
    for (int o = 0; o < PN; o++){
        float pe = bsh[o];
        #pragma unroll
        for (int p = 0; p < PN; p++) pe += col[p] * Wsh[o*PN + p];
        float pv = pe * inv_ls;
        uint16_t h = f2b(pv);
        xb[o] = h;
        qb[o] = f2b(c1f * pv);
        float xr = b2f(h);
        sq += xr * xr;
    }

    size_t base = ((size_t)b*SN + s) * PAUG;
    v8s pk[8];
    #pragma unroll
    for (int c = 0; c < 4; c++)
        #pragma unroll
        for (int j = 0; j < 8; j++) ((short*)&pk[c])[j] = (short)xb[c*8 + j];
    #pragma unroll
    for (int c = 4; c < 8; c++)
        #pragma unroll
        for (int j = 0; j < 8; j++) ((short*)&pk[c])[j] = 0;
    ((short*)&pk[4])[0] = (short)f2b(-0.5f * sq);
    ((short*)&pk[4])[1] = (short)0x3F80;   // 1.0
    #pragma unroll
    for (int c = 0; c < 8; c++) *(v8s*)(xk + base + c*8) = pk[c];

    #pragma unroll
    for (int c = 0; c < 4; c++)
        #pragma unroll
        for (int j = 0; j < 8; j++) ((short*)&pk[c])[j] = (short)qb[c*8 + j];
    ((short*)&pk[4])[0] = (short)f2b(c1f);
    ((short*)&pk[4])[1] = (short)f2b(-0.5f * sq * c1f);
    #pragma unroll
    for (int c = 0; c < 8; c++) *(v8s*)(xq + base + c*8) = pk[c];
}

// ---------------------------------------------------------------------------
// gemm_t (64x64 tile) -- kept ONLY for the Wv projection (EPI 3: fragment-
// ordered V store for attn).
// ---------------------------------------------------------------------------
template<int EPI, typename OutT>
__global__ __launch_bounds__(256) void gemm_t(
    const bf16_t* __restrict__ A, const bf16_t* __restrict__ W,
    const float* __restrict__ bias, OutT* __restrict__ out,
    bf16_t* __restrict__ vt, int N, int K)
{
    __shared__ __align__(16) bf16_t At[2][4096];   // 2 x 8 KB
    __shared__ __align__(16) bf16_t Wt[2][4096];   // 2 x 8 KB
    int tid = threadIdx.x;
    int lane = tid & 63, wv = tid >> 6, col = lane & 15, quad = lane >> 4;
    int m0 = blockIdx.x * 64, n0 = blockIdx.y * 64;
    int nck = K >> 6;

    int srow = tid >> 3;                      // 0..31
    int spc  = (tid & 7) ^ (srow & 7);        // swizzled source piece
    const bf16_t* asrc = A + (size_t)(m0 + srow)*K + spc*8;
    const bf16_t* wsrc = W + (size_t)(n0 + srow)*K + spc*8;

    v4f acc[4];
    #pragma unroll
    for (int t = 0; t < 4; t++) acc[t] = (v4f){0.f,0.f,0.f,0.f};

    // stage chunk 0
    glds16(asrc, &At[0][tid*8]);
    glds16(asrc + (size_t)32*K, &At[0][2048 + tid*8]);
    glds16(wsrc, &Wt[0][tid*8]);
    glds16(wsrc + (size_t)32*K, &Wt[0][2048 + tid*8]);
    __syncthreads();

    for (int c = 0; c < nck; c++){
        int cb = c & 1;
        if (c + 1 < nck){
            glds16(asrc + (c+1)*64, &At[cb^1][tid*8]);
            glds16(asrc + (size_t)32*K + (c+1)*64, &At[cb^1][2048 + tid*8]);
            glds16(wsrc + (c+1)*64, &Wt[cb^1][tid*8]);
            glds16(wsrc + (size_t)32*K + (c+1)*64, &Wt[cb^1][2048 + tid*8]);
        }
        #pragma unroll
        for (int kc = 0; kc < 2; kc++){
            int pc = ((kc*4 + quad) ^ (col & 7)) * 8;
            bf16x8 a = ldb8(&At[cb][(wv*16 + col)*64 + pc]);
            #pragma unroll
            for (int t = 0; t < 4; t++){
                bf16x8 b = ldb8(&Wt[cb][(t*16 + col)*64 + pc]);
                acc[t] = MFMA16(a, b, acc[t]);
            }
        }
        __syncthreads();
    }

    float bfv[4];
    #pragma unroll
    for (int t = 0; t < 4; t++) bfv[t] = bias[n0 + t*16 + col];

    if constexpr (EPI == 3){
        __shared__ uint16_t Tsh[64*74];
        #pragma unroll
        for (int r = 0; r < 4; r++)
            #pragma unroll
            for (int t = 0; t < 4; t++)
                Tsh[(wv*16 + quad*4 + r)*74 + t*16 + col] = f2b(acc[t][r] + bfv[t]);
        __syncthreads();
        int e = tid >> 2, sc = tid & 3;
        int b = m0 >> 12;
        int sbat = m0 & (SN-1);
        int eb   = (n0 + e) >> 5;
        int l31e = (n0 + e) & 31;
        int k16  = (sbat >> 4) + sc;
        v8s p0, p1;
        #pragma unroll
        for (int i = 0; i < 8; i++) ((short*)&p0)[i] = (short)Tsh[(sc*16 + i)*74 + e];
        #pragma unroll
        for (int i = 0; i < 8; i++) ((short*)&p1)[i] = (short)Tsh[(sc*16 + 8 + i)*74 + e];
        bf16_t* dst = vt + ((((size_t)b*8 + eb)*256 + k16)*64 + l31e)*8;
        *(v8s*)dst = p0;              // half 0 (keys s&15 in 0..7)
        *(v8s*)(dst + 256) = p1;      // half 1 (keys s&15 in 8..15), +32 lanes
    } else {
        #pragma unroll
        for (int r = 0; r < 4; r++){
            int row = m0 + wv*16 + quad*4 + r;
            #pragma unroll
            for (int t = 0; t < 4; t++){
                float y = acc[t][r] + bfv[t];
                if constexpr (EPI == 1) y = fmaxf(y, 0.f);
                stsc(out + (size_t)row*N + n0 + t*16 + col, y);
            }
        }
    }
}

// ---------------------------------------------------------------------------
// gemm128: out = A @ W^T + bias (opt relu). 128m x 128n tile, 256 thr.
// Used for W1 (N=1024). EPI 0: bias ; 1: bias+relu.
// ---------------------------------------------------------------------------
template<int EPI>
__global__ __launch_bounds__(256, 2) void gemm128(
    const bf16_t* __restrict__ A, const bf16_t* __restrict__ W,
    const float* __restrict__ bias, bf16_t* __restrict__ out,
    int N, int K)
{
    __shared__ __align__(16) bf16_t At[2][8192];   // 2 x 16 KB (128 rows x 64)
    __shared__ __align__(16) bf16_t Wt[2][8192];   // 2 x 16 KB
    int tid = threadIdx.x;
    int lane = tid & 63, wv = tid >> 6, col = lane & 15, quad = lane >> 4;
    int m0 = blockIdx.x * 128, n0 = blockIdx.y * 128;
    int nck = K >> 6;

    int srow = tid >> 3;                      // 0..31
    int spc  = (tid & 7) ^ (srow & 7);        // swizzled source piece
    const bf16_t* asrc = A + (size_t)(m0 + srow)*K + spc*8;
    const bf16_t* wsrc = W + (size_t)(n0 + srow)*K + spc*8;

    v4f acc[2][8];
    #pragma unroll
    for (int mi = 0; mi < 2; mi++)
        #pragma unroll
        for (int t = 0; t < 8; t++) acc[mi][t] = (v4f){0.f,0.f,0.f,0.f};

    // stage chunk 0: 4 row-groups of 32 per matrix
    #pragma unroll
    for (int s = 0; s < 4; s++){
        glds16(asrc + (size_t)(s*32)*K, &At[0][s*2048 + tid*8]);
        glds16(wsrc + (size_t)(s*32)*K, &Wt[0][s*2048 + tid*8]);
    }
    __syncthreads();

    for (int c = 0; c < nck; c++){
        int cb = c & 1;
        if (c + 1 < nck){
            #pragma unroll
            for (int s = 0; s < 4; s++){
                glds16(asrc + (size_t)(s*32)*K + (c+1)*64, &At[cb^1][s*2048 + tid*8]);
                glds16(wsrc + (size_t)(s*32)*K + (c+1)*64, &Wt[cb^1][s*2048 + tid*8]);
            }
        }
        #pragma unroll
        for (int kc = 0; kc < 2; kc++){
            int pc = ((kc*4 + quad) ^ (col & 7)) * 8;
            bf16x8 a[2];
            #pragma unroll
            for (int mi = 0; mi < 2; mi++)
                a[mi] = ldb8(&At[cb][(wv*32 + mi*16 + col)*64 + pc]);
            #pragma unroll
            for (int t = 0; t < 8; t++){
                bf16x8 b = ldb8(&Wt[cb][(t*16 + col)*64 + pc]);
                #pragma unroll
                for (int mi = 0; mi < 2; mi++)
                    acc[mi][t] = MFMA16(a[mi], b, acc[mi][t]);
            }
        }
        __syncthreads();
    }

    float bfv[8];
    #pragma unroll
    for (int t = 0; t < 8; t++) bfv[t] = bias[n0 + t*16 + col];

    #pragma unroll
    for (int mi = 0; mi < 2; mi++){
        #pragma unroll
        for (int r = 0; r < 4; r++){
            int row = m0 + wv*32 + mi*16 + quad*4 + r;
            #pragma unroll
            for (int t = 0; t < 8; t++){
                float y = acc[mi][t][r] + bfv[t];
                if constexpr (EPI == 1) y = fmaxf(y, 0.f);
                out[(size_t)row*N + n0 + t*16 + col] = f2b(y);
            }
        }
    }
}

// ---------------------------------------------------------------------------
// gemm_ln: out = LayerNorm(A @ W^T + bias + res) * gamma + beta.
// FULL-ROW tiles: 32m x 256n (= all of EN) per block -> LN fuses in epilogue.
// Grid BS/32 = 512 blocks (2/CU), 512 thr = 8 waves in 2m x 4n layout; each
// wave 16m x 64n (acc[4] v4f). Staging identical in spirit to gemm_t: BK=64
// double-buffered, global_load_lds 16B, source-side XOR piece-swizzle,
// 128 B LDS rows -> b128 fragment reads 2-way-free. LDS 73 KB.
// Row stats: shfl_xor over 16 col-lanes, then cross-n-wave combine via 1 KB
// LDS. Removes the standalone ln_kernel dispatches + y1/y2 round-trips.
// NOTE: out may alias A (full-row tiling: a block writes exactly the rows it
// has fully consumed as A before the epilogue).
// ---------------------------------------------------------------------------
template<typename OutT>
__global__ __launch_bounds__(512, 4) void gemm_ln(
    const bf16_t* __restrict__ A, const bf16_t* __restrict__ W,
    const float* __restrict__ bias, const bf16_t* __restrict__ res,
    const float* __restrict__ gamma, const float* __restrict__ beta,
    OutT* __restrict__ out, int K)
{
    __shared__ __align__(16) bf16_t At[2][32*64];    // 8 KB
    __shared__ __align__(16) bf16_t Wt[2][256*64];   // 64 KB
    __shared__ float lnb[4][32][2];                  // 1 KB

    int tid = threadIdx.x;
    int lane = tid & 63, wv = tid >> 6, col = lane & 15, quad = lane >> 4;
    int mw = wv >> 2;             // 0..1  (m-wave)
    int nw = wv & 3;              // 0..3  (n-wave)
    int m0 = blockIdx.x * 32;
    int nck = K >> 6;

    // staging addresses (source-side XOR piece swizzle, linear LDS dest)
    int arow = (tid & 255) >> 3;                 // 0..31 (tid<256 stages A)
    int apc  = (tid & 7) ^ (arow & 7);
    const bf16_t* asrc = A + (size_t)(m0 + arow)*K + apc*8;
    int wr0  = tid >> 3;                         // 0..63
    const bf16_t* wsrc[4];
    #pragma unroll
    for (int s = 0; s < 4; s++){
        int wrow = s*64 + wr0;
        int wpc  = (tid & 7) ^ (wrow & 7);
        wsrc[s] = W + (size_t)wrow*K + wpc*8;
    }

    v4f acc[4];
    #pragma unroll
    for (int t = 0; t < 4; t++) acc[t] = (v4f){0.f,0.f,0.f,0.f};

    // stage chunk 0
    if (tid < 256) glds16(asrc, &At[0][tid*8]);
    #pragma unroll
    for (int s = 0; s < 4; s++) glds16(wsrc[s], &Wt[0][s*4096 + tid*8]);
    __syncthreads();

    for (int c = 0; c < nck; c++){
        int cb = c & 1;
        if (c + 1 < nck){
            if (tid < 256) glds16(asrc + (c+1)*64, &At[cb^1][tid*8]);
            #pragma unroll
            for (int s = 0; s < 4; s++)
                glds16(wsrc[s] + (c+1)*64, &Wt[cb^1][s*4096 + tid*8]);
        }
        #pragma unroll
        for (int kc = 0; kc < 2; kc++){
            int pc = ((kc*4 + quad) ^ (col & 7)) * 8;
            bf16x8 a = ldb8(&At[cb][(mw*16 + col)*64 + pc]);
            #pragma unroll
            for (int t = 0; t < 4; t++){
                bf16x8 b = ldb8(&Wt[cb][(nw*64 + t*16 + col)*64 + pc]);
                acc[t] = MFMA16(a, b, acc[t]);
            }
        }
        __syncthreads();
    }

    // ---- fused LayerNorm epilogue ----
    float bfv[4];
    #pragma unroll
    for (int t = 0; t < 4; t++) bfv[t] = bias[nw*64 + t*16 + col];

    float v[4][4];        // [t][r]
    float s1[4], s2[4];   // per r
    #pragma unroll
    for (int r = 0; r < 4; r++){ s1[r] = 0.f; s2[r] = 0.f; }
    #pragma unroll
    for (int r = 0; r < 4; r++){
        int row = m0 + mw*16 + quad*4 + r;
        #pragma unroll
        for (int t = 0; t < 4; t++){
            float x = acc[t][r] + bfv[t]
                    + b2f(res[(size_t)row*EN + nw*64 + t*16 + col]);
            v[t][r] = x; s1[r] += x; s2[r] += x*x;
        }
    }
    #pragma unroll
    for (int r = 0; r < 4; r++){
        #pragma unroll
        for (int m = 1; m <= 8; m <<= 1){
            s1[r] += __shfl_xor(s1[r], m);
            s2[r] += __shfl_xor(s2[r], m);
        }
    }
    if (col == 0){
        #pragma unroll
        for (int r = 0; r < 4; r++){
            int rl = mw*16 + quad*4 + r;
            lnb[nw][rl][0] = s1[r];
            lnb[nw][rl][1] = s2[r];
        }
    }
    __syncthreads();
    #pragma unroll
    for (int r = 0; r < 4; r++){
        int rl  = mw*16 + quad*4 + r;
        int row = m0 + rl;
        float S1 = lnb[0][rl][0] + lnb[1][rl][0] + lnb[2][rl][0] + lnb[3][rl][0];
        float S2 = lnb[0][rl][1] + lnb[1][rl][1] + lnb[2][rl][1] + lnb[3][rl][1];
        float mu = S1 * (1.f/256.f);
        float rs = rsqrtf(S2 * (1.f/256.f) - mu*mu + 1e-5f);
        #pragma unroll
        for (int t = 0; t < 4; t++){
            int gi = nw*64 + t*16 + col;
            stsc(out + (size_t)row*EN + gi, (v[t][r]-mu)*rs*gamma[gi] + beta[gi]);
        }
    }
}

// ---------------------------------------------------------------------------
// Attention (round-6 structure, unchanged): Q=64/block, grid 256, 512 thr.
// Chunk=128 keys, vfrag-in-regs PV, raw barrier (no vmcnt drain), Wtb parity
// double-buffer, kf prefetch.
// ---------------------------------------------------------------------------
__global__ __launch_bounds__(512, 4) void attn_kernel(
    const bf16_t* __restrict__ xk, const bf16_t* __restrict__ xq,
    const bf16_t* __restrict__ vf, const float* __restrict__ osp,
    bf16_t* __restrict__ ctx)
{
    __shared__ __align__(16) bf16_t Wtb[2][64*132];   // 33 KB
    __shared__ __align__(16) bf16_t Qs[64*64];        // 8 KB
    __shared__ float densh[8][64];                    // 2 KB
    __shared__ float dent[64];

    int tid  = threadIdx.x;
    int lane = tid & 63;
    int wv   = tid >> 6;          // 0..7
    int col  = lane & 15;
    int quad = lane >> 4;
    int l31  = lane & 31;
    int half = lane >> 5;

    // batch b pinned to XCD pair {2b,2b+1} -> its V slice L2-resident
    int bid = blockIdx.x;                    // 0..255
    int b   = (bid & 7) >> 1;
    int qi  = ((bid >> 3) << 1) | (bid & 1); // 0..63
    int q0  = qi * 64;

    float k2 = 1.4426950408889634f * osp[0];

    const bf16_t* xkb = xk + (size_t)b * SN * PAUG;
    const bf16_t* xqb = xq + (size_t)b * SN * PAUG;
    // this wave's V-fragment stream: [k16 = 0..255][lane][8]
    const bf16_t* vfb = vf + (((size_t)b*8 + wv)*256)*512 + lane*8;

    // stage Q tile: 512 thr x 16 B = 8 KB, piece-swizzled SOURCE, linear dest
    {
        int qrow = tid >> 3;                 // 0..63
        int qpc  = (tid & 7) ^ (qrow & 7);
        glds16(xqb + (size_t)(q0 + qrow)*PAUG + qpc*8, &Qs[tid*8]);
    }

    v16f acc[2];
    #pragma unroll
    for (int qg = 0; qg < 2; qg++)
        #pragma unroll
        for (int i = 0; i < 16; i++) acc[qg][i] = 0.f;
    float den[4] = {0.f, 0.f, 0.f, 0.f};     // [qg*2+g2]
    const v4f zero = (v4f){0.f,0.f,0.f,0.f};

    // kf prologue (chunk 0): this wave's 16 keys, 2 paug-halves
    bf16x8 kf0, kf1;
    {
        const bf16_t* kr = xkb + (size_t)(wv*16 + col)*PAUG + quad*8;
        kf0 = ldb8(kr); kf1 = ldb8(kr + 32);
    }

    __syncthreads();   // Qs staged (one-time full drain)

    for (int c = 0; c < 32; c++){
        int cb = c & 1;
        // issue V(c): 8 coalesced b128 into regs (QK covers L2 latency)
        bf16x8 vr[8];
        #pragma unroll
        for (int sk = 0; sk < 8; sk++)
            vr[sk] = ldb8(vfb + (size_t)(c*8 + sk)*512);

        // QK + exp: this wave's 16-key slice x 64 q of chunk c
        #pragma unroll
        for (int qg = 0; qg < 2; qg++){
            #pragma unroll
            for (int g2 = 0; g2 < 2; g2++){
                int qr = qg*32 + g2*16 + col;
                bf16x8 qa = ldb8(&Qs[qr*64 + ((quad    ) ^ (col & 7))*8]);
                bf16x8 qb = ldb8(&Qs[qr*64 + ((4 + quad) ^ (col & 7))*8]);
                v4f st = MFMA16(kf0, qa, zero);
                st = MFMA16(kf1, qb, st);
                #pragma unroll
                for (int rp = 0; rp < 2; rp++){
                    float w0 = fexp2(fmaf(k2, fexp2(st[rp*2+0]), -k2));
                    float w1 = fexp2(fmaf(k2, fexp2(st[rp*2+1]), -k2));
                    den[qg*2+g2] += w0 + w1;
                    *(uint32_t*)&Wtb[cb][qr*132 + wv*16 + quad*4 + rp*2]
                        = pkbf16(w0, w1);
                }
            }
        }

        // prefetch kf(c+1) (global load, stays in flight across raw barrier)
        if (c + 1 < 32){
            const bf16_t* kr = xkb + (size_t)((c+1)*128 + wv*16 + col)*PAUG + quad*8;
            kf0 = ldb8(kr); kf1 = ldb8(kr + 32);
        }

        // LDS-visibility barrier WITHOUT vmcnt drain
        asm volatile("s_waitcnt lgkmcnt(0)" ::: "memory");
        __builtin_amdgcn_s_barrier();
        __builtin_amdgcn_sched_barrier(0);

        // PV chunk c: this wave's 32-e slice, 2 qg x 8 MFMA32 over k=128
        #pragma unroll
        for (int qg = 0; qg < 2; qg++){
            #pragma unroll
            for (int sk4 = 0; sk4 < 2; sk4++){
                bf16x8 af[4];
                #pragma unroll
                for (int j = 0; j < 4; j++)
                    af[j] = ldb8u(&Wtb[cb][(qg*32 + l31)*132 + (sk4*4 + j)*16 + half*8]);
                #pragma unroll
                for (int j = 0; j < 4; j++)
                    acc[qg] = MFMA32(af[j], vr[sk4*4 + j], acc[qg]);
            }
        }
    }

    #pragma unroll
    for (int d = 0; d < 4; d++){
        den[d] += __shfl_xor(den[d], 16);
        den[d] += __shfl_xor(den[d], 32);
    }
    if (lane < 16){
        #pragma unroll
        for (int qg = 0; qg < 2; qg++)
            #pragma unroll
            for (int g2 = 0; g2 < 2; g2++)
                densh[wv][qg*32 + g2*16 + lane] = den[qg*2+g2];
    }
    __syncthreads();
    if (tid < 64){
        float s = 0.f;
        #pragma unroll
        for (int w = 0; w < 8; w++) s += densh[w][tid];
        dent[tid] = 1.f / s;
    }
    __syncthreads();

    size_t obase = ((size_t)b*SN + q0) * EN + wv*32;
    #pragma unroll
    for (int qg = 0; qg < 2; qg++){
        #pragma unroll
        for (int rg = 0; rg < 16; rg++){
            int row = (rg & 3) + 8*(rg >> 2) + 4*half;
            float inv = dent[qg*32 + row];
            ctx[obase + (size_t)(qg*32 + row)*EN + l31] = f2b(acc[qg][rg] * inv);
        }
    }
}

// ---------------------------------------------------------------------------
extern "C" void kernel_launch(void* const* d_in, const int* in_sizes, int n_in,
                              void* d_out, int out_size, void* d_ws, size_t ws_size,
                              hipStream_t stream)
{
    (void)in_sizes; (void)n_in; (void)out_size; (void)ws_size;
    const float* src  = (const float*)d_in[0];
    const float* pos  = (const float*)d_in[1];
    const float* Wpos = (const float*)d_in[2];
    const float* bpos = (const float*)d_in[3];
    const float* ls   = (const float*)d_in[4];
    const float* os   = (const float*)d_in[5];
    const float* Wv   = (const float*)d_in[6];
    const float* bv   = (const float*)d_in[7];
    const float* Wo   = (const float*)d_in[8];
    const float* bo   = (const float*)d_in[9];
    const float* W1   = (const float*)d_in[10];
    const float* b1   = (const float*)d_in[11];
    const float* W2   = (const float*)d_in[12];
    const float* b2   = (const float*)d_in[13];
    const float* g1   = (const float*)d_in[14];
    const float* be1  = (const float*)d_in[15];
    const float* g2   = (const float*)d_in[16];
    const float* be2  = (const float*)d_in[17];

    char* w = (char*)d_ws;
    bf16_t* xkb  = (bf16_t*)(w);                         // 2 MB [B,S,64]
    bf16_t* xqb  = (bf16_t*)(w + ( 2u<<20));             // 2 MB
    bf16_t* Wvb  = (bf16_t*)(w + ( 4u<<20));             // 128 KB
    bf16_t* Wob  = (bf16_t*)(w + ( 4u<<20) + (1u<<18));  // 128 KB
    bf16_t* W1b  = (bf16_t*)(w + ( 5u<<20));             // 512 KB
    bf16_t* W2b  = (bf16_t*)(w + ( 6u<<20));             // 512 KB
    bf16_t* srcb = (bf16_t*)(w + ( 8u<<20));             // 8 MB (alive thru gemm_ln#1)
    bf16_t* vtg  = (bf16_t*)(w + (16u<<20));             // 8 MB vfrag (dead after attn)
    bf16_t* ctx  = (bf16_t*)(w + (24u<<20));             // 8 MB
    bf16_t* xws  = (bf16_t*)(w + (24u<<20));             // aliases ctx (safe: full-row tiles)
    bf16_t* hws  = (bf16_t*)(w + (32u<<20));             // 32 MB

    prep_kernel<<<dim3(4800), 256, 0, stream>>>(
        src, srcb, Wv, Wvb, Wo, Wob, W1, W1b, W2, W2b,
        pos, Wpos, bpos, ls, xkb, xqb);

    // v = src @ Wv^T + bv  -> fragment-ordered store vfrag[b][eb][k16][lane][8]
    gemm_t<3, bf16_t><<<dim3(BS/64, EN/64), 256, 0, stream>>>(
        srcb, Wvb, bv, (bf16_t*)nullptr, vtg, EN, EN);
    // ctx = softmax(os*exp(-0.5*d2)) @ v
    attn_kernel<<<dim3(256), 512, 0, stream>>>(xkb, xqb, vtg, os, ctx);
    // x = LN1(ctx @ Wo^T + bo + src)  [fused gemm+LN; out aliases A row-safe]
    gemm_ln<bf16_t><<<dim3(BS/32), 512, 0, stream>>>(
        ctx, Wob, bo, srcb, g1, be1, xws, EN);
    // h = relu(x @ W1^T + b1)
    gemm128<1><<<dim3(BS/128, FN/128), 256, 0, stream>>>(
        xws, W1b, b1, hws, FN, EN);
    // out = LN2(h @ W2^T + b2 + x) -> fp32  [fused gemm+LN]
    gemm_ln<float><<<dim3(BS/32), 512, 0, stream>>>(
        hws, W2b, b2, xws, g2, be2, (float*)d_out, FN);
}

// Round 9
// 231.899 us; speedup vs baseline: 1.0733x; 1.0027x over previous
//
#include <hip/hip_runtime.h>
#include <stdint.h>

#define BN 4
#define SN 4096
#define EN 256
#define PN 32
#define FN 1024
#define BS (BN*SN)   // 16384
#define PAUG 64      // 32 xs chans + aug (+ zero pad to 64)

typedef uint16_t bf16_t;
typedef short v4s  __attribute__((ext_vector_type(4)));
typedef short v8s  __attribute__((ext_vector_type(8)));
typedef __bf16 bf16x8 __attribute__((ext_vector_type(8)));
typedef float v4f   __attribute__((ext_vector_type(4)));
typedef float v16f  __attribute__((ext_vector_type(16)));

#define MFMA16(a,b,c) __builtin_amdgcn_mfma_f32_16x16x32_bf16(a,b,c,0,0,0)
#define MFMA32(a,b,c) __builtin_amdgcn_mfma_f32_32x32x16_bf16(a,b,c,0,0,0)

__device__ __forceinline__ float b2f(bf16_t x){
    uint32_t u = ((uint32_t)x) << 16; float f; __builtin_memcpy(&f, &u, 4); return f;
}
__device__ __forceinline__ bf16_t f2b(float f){
    uint32_t u; __builtin_memcpy(&u, &f, 4);
    u += 0x7FFFu + ((u >> 16) & 1u);           // RNE
    return (bf16_t)(u >> 16);
}
__device__ __forceinline__ bf16x8 ldb8(const bf16_t* p){
    v8s r = *(const v8s*)p; return __builtin_bit_cast(bf16x8, r);
}
// 8-B-aligned load pair (for LDS rows with odd 8-B stride -> 2-way-free banks)
__device__ __forceinline__ bf16x8 ldb8u(const bf16_t* p){
    v4s lo = *(const v4s*)p;
    v4s hi = *(const v4s*)(p + 4);
    v8s r = __builtin_shufflevector(lo, hi, 0,1,2,3,4,5,6,7);
    return __builtin_bit_cast(bf16x8, r);
}
__device__ __forceinline__ float ldsc(const float* p){ return *p; }
__device__ __forceinline__ float ldsc(const bf16_t* p){ return b2f(*p); }
__device__ __forceinline__ void stsc(float* p, float v){ *p = v; }
__device__ __forceinline__ void stsc(bf16_t* p, float v){ *p = f2b(v); }

#if __has_builtin(__builtin_amdgcn_exp2f)
__device__ __forceinline__ float fexp2(float x){ return __builtin_amdgcn_exp2f(x); }
#else
__device__ __forceinline__ float fexp2(float x){ return exp2f(x); }
#endif

#if __has_builtin(__builtin_amdgcn_cvt_pk_bf16_f32)
typedef __bf16 bf16x2 __attribute__((ext_vector_type(2)));
__device__ __forceinline__ uint32_t pkbf16(float a, float b){
    bf16x2 r = __builtin_amdgcn_cvt_pk_bf16_f32(a, b);
    return __builtin_bit_cast(uint32_t, r);
}
#else
__device__ __forceinline__ uint32_t pkbf16(float a, float b){
    return (uint32_t)f2b(a) | ((uint32_t)f2b(b) << 16);
}
#endif

typedef const __attribute__((address_space(1))) uint32_t* glds_gp;
typedef __attribute__((address_space(3))) uint32_t* glds_lp;
__device__ __forceinline__ void glds16(const bf16_t* g, bf16_t* l){
    __builtin_amdgcn_global_load_lds((glds_gp)g, (glds_lp)l, 16, 0, 0);
}

// ---------------------------------------------------------------------------
// prep: (a) src fp32->bf16, (b) weight cvts (Wo -> MFMA16-B FRAGMENT order),
// (c) posxs. One launch.
// Wofrag layout: [nblk=n>>4][kch=k>>5][lane=((k>>3)&3)*16 + (n&15)][j=k&7]
// so attn's Wo-gemm B-loads are coalesced b128 straight from global.
// ---------------------------------------------------------------------------
__global__ __launch_bounds__(256) void prep_kernel(
    const float* __restrict__ src, bf16_t* __restrict__ srcb,
    const float* __restrict__ Wv, bf16_t* __restrict__ Wvb,
    const float* __restrict__ Wo, bf16_t* __restrict__ Wob,
    const float* __restrict__ W1, bf16_t* __restrict__ W1b,
    const float* __restrict__ W2, bf16_t* __restrict__ W2b,
    const float* __restrict__ pos, const float* __restrict__ Wp,
    const float* __restrict__ bp,  const float* __restrict__ lsp,
    bf16_t* __restrict__ xk, bf16_t* __restrict__ xq)
{
    __shared__ float Wsh[PN*PN];
    __shared__ float bsh[PN];
    int bid = blockIdx.x;
    int tid = threadIdx.x;

    if (bid < 4736){
        const float* sp; bf16_t* dp; int off;
        if (bid < 4096){ sp = src; dp = srcb; off = (bid*256 + tid)*4; }
        else {
            int i = ((bid - 4096)*256 + tid)*4;
            if      (i <  65536){ sp=Wv; dp=Wvb; off=i; }
            else if (i < 131072){
                // Wo -> fragment order
                int idx = i - 65536;
                float4 f = *(const float4*)(Wo + idx);
                v4s o;
                o.x = (short)f2b(f.x); o.y = (short)f2b(f.y);
                o.z = (short)f2b(f.z); o.w = (short)f2b(f.w);
                int n = idx >> 8, k = idx & 255;
                int dst = (((n>>4)*8 + (k>>5))*64 + (((k>>3)&3)*16 + (n&15)))*8 + (k&7);
                *(v4s*)(Wob + dst) = o;
                return;
            }
            else if (i < 393216){ sp=W1; dp=W1b; off=i-131072; }
            else                { sp=W2; dp=W2b; off=i-393216; }
        }
        float4 f = *(const float4*)(sp + off);
        v4s o;
        o.x = (short)f2b(f.x); o.y = (short)f2b(f.y);
        o.z = (short)f2b(f.z); o.w = (short)f2b(f.w);
        *(v4s*)(dp + off) = o;
        return;
    }

    int pb = bid - 4736;          // 0..63
    int b  = pb >> 4;
    int s  = (pb & 15)*256 + tid;

    for (int i = tid; i < PN*PN; i += 256) Wsh[i] = Wp[i];
    if (tid < PN) bsh[tid] = bp[tid];
    __syncthreads();

    float inv_ls = 1.0f / lsp[0];
    const float c1f = 1.4426950408889634f;

    float col[PN];
    #pragma unroll
    for (int p = 0; p < PN; p++) col[p] = pos[((size_t)b*PN + p)*SN + s];

    uint16_t xb[PN], qb[PN];
    float sq = 0.f;
    #pragma unroll 4
    for (int o = 0; o < PN; o++){
        float pe = bsh[o];
        #pragma unroll
        for (int p = 0; p < PN; p++) pe += col[p] * Wsh[o*PN + p];
        float pv = pe * inv_ls;
        uint16_t h = f2b(pv);
        xb[o] = h;
        qb[o] = f2b(c1f * pv);
        float xr = b2f(h);
        sq += xr * xr;
    }

    size_t base = ((size_t)b*SN + s) * PAUG;
    v8s pk[8];
    #pragma unroll
    for (int c = 0; c < 4; c++)
        #pragma unroll
        for (int j = 0; j < 8; j++) ((short*)&pk[c])[j] = (short)xb[c*8 + j];
    #pragma unroll
    for (int c = 4; c < 8; c++)
        #pragma unroll
        for (int j = 0; j < 8; j++) ((short*)&pk[c])[j] = 0;
    ((short*)&pk[4])[0] = (short)f2b(-0.5f * sq);
    ((short*)&pk[4])[1] = (short)0x3F80;   // 1.0
    #pragma unroll
    for (int c = 0; c < 8; c++) *(v8s*)(xk + base + c*8) = pk[c];

    #pragma unroll
    for (int c = 0; c < 4; c++)
        #pragma unroll
        for (int j = 0; j < 8; j++) ((short*)&pk[c])[j] = (short)qb[c*8 + j];
    ((short*)&pk[4])[0] = (short)f2b(c1f);
    ((short*)&pk[4])[1] = (short)f2b(-0.5f * sq * c1f);
    #pragma unroll
    for (int c = 0; c < 8; c++) *(v8s*)(xq + base + c*8) = pk[c];
}

// ---------------------------------------------------------------------------
// gemm_t (64x64 tile) -- kept ONLY for the Wv projection (EPI 3: fragment-
// ordered V store for attn).
// ---------------------------------------------------------------------------
template<int EPI, typename OutT>
__global__ __launch_bounds__(256) void gemm_t(
    const bf16_t* __restrict__ A, const bf16_t* __restrict__ W,
    const float* __restrict__ bias, OutT* __restrict__ out,
    bf16_t* __restrict__ vt, int N, int K)
{
    __shared__ __align__(16) bf16_t At[2][4096];   // 2 x 8 KB
    __shared__ __align__(16) bf16_t Wt[2][4096];   // 2 x 8 KB
    int tid = threadIdx.x;
    int lane = tid & 63, wv = tid >> 6, col = lane & 15, quad = lane >> 4;
    int m0 = blockIdx.x * 64, n0 = blockIdx.y * 64;
    int nck = K >> 6;

    int srow = tid >> 3;                      // 0..31
    int spc  = (tid & 7) ^ (srow & 7);        // swizzled source piece
    const bf16_t* asrc = A + (size_t)(m0 + srow)*K + spc*8;
    const bf16_t* wsrc = W + (size_t)(n0 + srow)*K + spc*8;

    v4f acc[4];
    #pragma unroll
    for (int t = 0; t < 4; t++) acc[t] = (v4f){0.f,0.f,0.f,0.f};

    // stage chunk 0
    glds16(asrc, &At[0][tid*8]);
    glds16(asrc + (size_t)32*K, &At[0][2048 + tid*8]);
    glds16(wsrc, &Wt[0][tid*8]);
    glds16(wsrc + (size_t)32*K, &Wt[0][2048 + tid*8]);
    __syncthreads();

    for (int c = 0; c < nck; c++){
        int cb = c & 1;
        if (c + 1 < nck){
            glds16(asrc + (c+1)*64, &At[cb^1][tid*8]);
            glds16(asrc + (size_t)32*K + (c+1)*64, &At[cb^1][2048 + tid*8]);
            glds16(wsrc + (c+1)*64, &Wt[cb^1][tid*8]);
            glds16(wsrc + (size_t)32*K + (c+1)*64, &Wt[cb^1][2048 + tid*8]);
        }
        #pragma unroll
        for (int kc = 0; kc < 2; kc++){
            int pc = ((kc*4 + quad) ^ (col & 7)) * 8;
            bf16x8 a = ldb8(&At[cb][(wv*16 + col)*64 + pc]);
            #pragma unroll
            for (int t = 0; t < 4; t++){
                bf16x8 b = ldb8(&Wt[cb][(t*16 + col)*64 + pc]);
                acc[t] = MFMA16(a, b, acc[t]);
            }
        }
        __syncthreads();
    }

    float bfv[4];
    #pragma unroll
    for (int t = 0; t < 4; t++) bfv[t] = bias[n0 + t*16 + col];

    if constexpr (EPI == 3){
        __shared__ uint16_t Tsh[64*74];
        #pragma unroll
        for (int r = 0; r < 4; r++)
            #pragma unroll
            for (int t = 0; t < 4; t++)
                Tsh[(wv*16 + quad*4 + r)*74 + t*16 + col] = f2b(acc[t][r] + bfv[t]);
        __syncthreads();
        int e = tid >> 2, sc = tid & 3;
        int b = m0 >> 12;
        int sbat = m0 & (SN-1);
        int eb   = (n0 + e) >> 5;
        int l31e = (n0 + e) & 31;
        int k16  = (sbat >> 4) + sc;
        v8s p0, p1;
        #pragma unroll
        for (int i = 0; i < 8; i++) ((short*)&p0)[i] = (short)Tsh[(sc*16 + i)*74 + e];
        #pragma unroll
        for (int i = 0; i < 8; i++) ((short*)&p1)[i] = (short)Tsh[(sc*16 + 8 + i)*74 + e];
        bf16_t* dst = vt + ((((size_t)b*8 + eb)*256 + k16)*64 + l31e)*8;
        *(v8s*)dst = p0;              // half 0 (keys s&15 in 0..7)
        *(v8s*)(dst + 256) = p1;      // half 1 (keys s&15 in 8..15), +32 lanes
    } else {
        #pragma unroll
        for (int r = 0; r < 4; r++){
            int row = m0 + wv*16 + quad*4 + r;
            #pragma unroll
            for (int t = 0; t < 4; t++){
                float y = acc[t][r] + bfv[t];
                if constexpr (EPI == 1) y = fmaxf(y, 0.f);
                stsc(out + (size_t)row*N + n0 + t*16 + col, y);
            }
        }
    }
}

// ---------------------------------------------------------------------------
// gemm128: out = A @ W^T + bias (opt relu). 128m x 128n tile, 256 thr.
// Used for W1 (N=1024). EPI 0: bias ; 1: bias+relu.
// ---------------------------------------------------------------------------
template<int EPI>
__global__ __launch_bounds__(256, 2) void gemm128(
    const bf16_t* __restrict__ A, const bf16_t* __restrict__ W,
    const float* __restrict__ bias, bf16_t* __restrict__ out,
    int N, int K)
{
    __shared__ __align__(16) bf16_t At[2][8192];   // 2 x 16 KB (128 rows x 64)
    __shared__ __align__(16) bf16_t Wt[2][8192];   // 2 x 16 KB
    int tid = threadIdx.x;
    int lane = tid & 63, wv = tid >> 6, col = lane & 15, quad = lane >> 4;
    int m0 = blockIdx.x * 128, n0 = blockIdx.y * 128;
    int nck = K >> 6;

    int srow = tid >> 3;                      // 0..31
    int spc  = (tid & 7) ^ (srow & 7);        // swizzled source piece
    const bf16_t* asrc = A + (size_t)(m0 + srow)*K + spc*8;
    const bf16_t* wsrc = W + (size_t)(n0 + srow)*K + spc*8;

    v4f acc[2][8];
    #pragma unroll
    for (int mi = 0; mi < 2; mi++)
        #pragma unroll
        for (int t = 0; t < 8; t++) acc[mi][t] = (v4f){0.f,0.f,0.f,0.f};

    // stage chunk 0: 4 row-groups of 32 per matrix
    #pragma unroll
    for (int s = 0; s < 4; s++){
        glds16(asrc + (size_t)(s*32)*K, &At[0][s*2048 + tid*8]);
        glds16(wsrc + (size_t)(s*32)*K, &Wt[0][s*2048 + tid*8]);
    }
    __syncthreads();

    for (int c = 0; c < nck; c++){
        int cb = c & 1;
        if (c + 1 < nck){
            #pragma unroll
            for (int s = 0; s < 4; s++){
                glds16(asrc + (size_t)(s*32)*K + (c+1)*64, &At[cb^1][s*2048 + tid*8]);
                glds16(wsrc + (size_t)(s*32)*K + (c+1)*64, &Wt[cb^1][s*2048 + tid*8]);
            }
        }
        #pragma unroll
        for (int kc = 0; kc < 2; kc++){
            int pc = ((kc*4 + quad) ^ (col & 7)) * 8;
            bf16x8 a[2];
            #pragma unroll
            for (int mi = 0; mi < 2; mi++)
                a[mi] = ldb8(&At[cb][(wv*32 + mi*16 + col)*64 + pc]);
            #pragma unroll
            for (int t = 0; t < 8; t++){
                bf16x8 b = ldb8(&Wt[cb][(t*16 + col)*64 + pc]);
                #pragma unroll
                for (int mi = 0; mi < 2; mi++)
                    acc[mi][t] = MFMA16(a[mi], b, acc[mi][t]);
            }
        }
        __syncthreads();
    }

    float bfv[8];
    #pragma unroll
    for (int t = 0; t < 8; t++) bfv[t] = bias[n0 + t*16 + col];

    #pragma unroll
    for (int mi = 0; mi < 2; mi++){
        #pragma unroll
        for (int r = 0; r < 4; r++){
            int row = m0 + wv*32 + mi*16 + quad*4 + r;
            #pragma unroll
            for (int t = 0; t < 8; t++){
                float y = acc[mi][t][r] + bfv[t];
                if constexpr (EPI == 1) y = fmaxf(y, 0.f);
                out[(size_t)row*N + n0 + t*16 + col] = f2b(y);
            }
        }
    }
}

// ---------------------------------------------------------------------------
// gemm_ln: out = LayerNorm(A @ W^T + bias + res) * gamma + beta.
// FULL-ROW tiles 32m x 256n. Used for W2+LN2. (Unchanged, verified round 8.)
// ---------------------------------------------------------------------------
template<typename OutT>
__global__ __launch_bounds__(512, 4) void gemm_ln(
    const bf16_t* __restrict__ A, const bf16_t* __restrict__ W,
    const float* __restrict__ bias, const bf16_t* __restrict__ res,
    const float* __restrict__ gamma, const float* __restrict__ beta,
    OutT* __restrict__ out, int K)
{
    __shared__ __align__(16) bf16_t At[2][32*64];    // 8 KB
    __shared__ __align__(16) bf16_t Wt[2][256*64];   // 64 KB
    __shared__ float lnb[4][32][2];                  // 1 KB

    int tid = threadIdx.x;
    int lane = tid & 63, wv = tid >> 6, col = lane & 15, quad = lane >> 4;
    int mw = wv >> 2;             // 0..1  (m-wave)
    int nw = wv & 3;              // 0..3  (n-wave)
    int m0 = blockIdx.x * 32;
    int nck = K >> 6;

    int arow = (tid & 255) >> 3;                 // 0..31 (tid<256 stages A)
    int apc  = (tid & 7) ^ (arow & 7);
    const bf16_t* asrc = A + (size_t)(m0 + arow)*K + apc*8;
    int wr0  = tid >> 3;                         // 0..63
    const bf16_t* wsrc[4];
    #pragma unroll
    for (int s = 0; s < 4; s++){
        int wrow = s*64 + wr0;
        int wpc  = (tid & 7) ^ (wrow & 7);
        wsrc[s] = W + (size_t)wrow*K + wpc*8;
    }

    v4f acc[4];
    #pragma unroll
    for (int t = 0; t < 4; t++) acc[t] = (v4f){0.f,0.f,0.f,0.f};

    if (tid < 256) glds16(asrc, &At[0][tid*8]);
    #pragma unroll
    for (int s = 0; s < 4; s++) glds16(wsrc[s], &Wt[0][s*4096 + tid*8]);
    __syncthreads();

    for (int c = 0; c < nck; c++){
        int cb = c & 1;
        if (c + 1 < nck){
            if (tid < 256) glds16(asrc + (c+1)*64, &At[cb^1][tid*8]);
            #pragma unroll
            for (int s = 0; s < 4; s++)
                glds16(wsrc[s] + (c+1)*64, &Wt[cb^1][s*4096 + tid*8]);
        }
        #pragma unroll
        for (int kc = 0; kc < 2; kc++){
            int pc = ((kc*4 + quad) ^ (col & 7)) * 8;
            bf16x8 a = ldb8(&At[cb][(mw*16 + col)*64 + pc]);
            #pragma unroll
            for (int t = 0; t < 4; t++){
                bf16x8 b = ldb8(&Wt[cb][(nw*64 + t*16 + col)*64 + pc]);
                acc[t] = MFMA16(a, b, acc[t]);
            }
        }
        __syncthreads();
    }

    float bfv[4];
    #pragma unroll
    for (int t = 0; t < 4; t++) bfv[t] = bias[nw*64 + t*16 + col];

    float v[4][4];
    float s1[4], s2[4];
    #pragma unroll
    for (int r = 0; r < 4; r++){ s1[r] = 0.f; s2[r] = 0.f; }
    #pragma unroll
    for (int r = 0; r < 4; r++){
        int row = m0 + mw*16 + quad*4 + r;
        #pragma unroll
        for (int t = 0; t < 4; t++){
            float x = acc[t][r] + bfv[t]
                    + b2f(res[(size_t)row*EN + nw*64 + t*16 + col]);
            v[t][r] = x; s1[r] += x; s2[r] += x*x;
        }
    }
    #pragma unroll
    for (int r = 0; r < 4; r++){
        #pragma unroll
        for (int m = 1; m <= 8; m <<= 1){
            s1[r] += __shfl_xor(s1[r], m);
            s2[r] += __shfl_xor(s2[r], m);
        }
    }
    if (col == 0){
        #pragma unroll
        for (int r = 0; r < 4; r++){
            int rl = mw*16 + quad*4 + r;
            lnb[nw][rl][0] = s1[r];
            lnb[nw][rl][1] = s2[r];
        }
    }
    __syncthreads();
    #pragma unroll
    for (int r = 0; r < 4; r++){
        int rl  = mw*16 + quad*4 + r;
        int row = m0 + rl;
        float S1 = lnb[0][rl][0] + lnb[1][rl][0] + lnb[2][rl][0] + lnb[3][rl][0];
        float S2 = lnb[0][rl][1] + lnb[1][rl][1] + lnb[2][rl][1] + lnb[3][rl][1];
        float mu = S1 * (1.f/256.f);
        float rs = rsqrtf(S2 * (1.f/256.f) - mu*mu + 1e-5f);
        #pragma unroll
        for (int t = 0; t < 4; t++){
            int gi = nw*64 + t*16 + col;
            stsc(out + (size_t)row*EN + gi, (v[t][r]-mu)*rs*gamma[gi] + beta[gi]);
        }
    }
}

// ---------------------------------------------------------------------------
// Attention round 17: round-6 main loop UNCHANGED; epilogue now fuses
//   O -> (LDS, XOR-piece-swizzled) -> y1 = O @ Wo^T + bo + res -> LN1 -> out
// Wo read pre-fragmented (Wofrag, coalesced b128 B-operands). Kills the
// ctx intermediate + the gemm_ln#1 dispatch.
// Grid 256 = 1 block/CU -> launch_bounds(512,2): VGPR cap 256, occupancy is
// grid-limited anyway (round-4 lesson: never let the allocator starve).
// ---------------------------------------------------------------------------
__global__ __launch_bounds__(512, 2) void attn_kernel(
    const bf16_t* __restrict__ xk, const bf16_t* __restrict__ xq,
    const bf16_t* __restrict__ vf, const float* __restrict__ osp,
    const bf16_t* __restrict__ wof, const float* __restrict__ bo,
    const bf16_t* __restrict__ res, const float* __restrict__ gamma,
    const float* __restrict__ beta, bf16_t* __restrict__ out)
{
    __shared__ __align__(16) bf16_t Wtb[2][64*132];   // 33 KB
    __shared__ __align__(16) bf16_t Qs[64*64];        // 8 KB
    __shared__ __align__(16) bf16_t Osh[64*256];      // 32 KB (O tile, swizzled)
    __shared__ float densh[8][64];                    // 2 KB
    __shared__ float dent[64];
    __shared__ float lnw[8][64][2];                   // 4 KB

    int tid  = threadIdx.x;
    int lane = tid & 63;
    int wv   = tid >> 6;          // 0..7
    int col  = lane & 15;
    int quad = lane >> 4;
    int l31  = lane & 31;
    int half = lane >> 5;

    // batch b pinned to XCD pair {2b,2b+1} -> its V slice L2-resident
    int bid = blockIdx.x;                    // 0..255
    int b   = (bid & 7) >> 1;
    int qi  = ((bid >> 3) << 1) | (bid & 1); // 0..63
    int q0  = qi * 64;

    float k2 = 1.4426950408889634f * osp[0];

    const bf16_t* xkb = xk + (size_t)b * SN * PAUG;
    const bf16_t* xqb = xq + (size_t)b * SN * PAUG;
    const bf16_t* vfb = vf + (((size_t)b*8 + wv)*256)*512 + lane*8;

    // stage Q tile: piece-swizzled SOURCE, linear dest
    {
        int qrow = tid >> 3;                 // 0..63
        int qpc  = (tid & 7) ^ (qrow & 7);
        glds16(xqb + (size_t)(q0 + qrow)*PAUG + qpc*8, &Qs[tid*8]);
    }

    v16f acc[2];
    #pragma unroll
    for (int qg = 0; qg < 2; qg++)
        #pragma unroll
        for (int i = 0; i < 16; i++) acc[qg][i] = 0.f;
    float den[4] = {0.f, 0.f, 0.f, 0.f};
    const v4f zero = (v4f){0.f,0.f,0.f,0.f};

    bf16x8 kf0, kf1;
    {
        const bf16_t* kr = xkb + (size_t)(wv*16 + col)*PAUG + quad*8;
        kf0 = ldb8(kr); kf1 = ldb8(kr + 32);
    }

    __syncthreads();   // Qs staged

    for (int c = 0; c < 32; c++){
        int cb = c & 1;
        bf16x8 vr[8];
        #pragma unroll
        for (int sk = 0; sk < 8; sk++)
            vr[sk] = ldb8(vfb + (size_t)(c*8 + sk)*512);

        #pragma unroll
        for (int qg = 0; qg < 2; qg++){
            #pragma unroll
            for (int g2 = 0; g2 < 2; g2++){
                int qr = qg*32 + g2*16 + col;
                bf16x8 qa = ldb8(&Qs[qr*64 + ((quad    ) ^ (col & 7))*8]);
                bf16x8 qb = ldb8(&Qs[qr*64 + ((4 + quad) ^ (col & 7))*8]);
                v4f st = MFMA16(kf0, qa, zero);
                st = MFMA16(kf1, qb, st);
                #pragma unroll
                for (int rp = 0; rp < 2; rp++){
                    float w0 = fexp2(fmaf(k2, fexp2(st[rp*2+0]), -k2));
                    float w1 = fexp2(fmaf(k2, fexp2(st[rp*2+1]), -k2));
                    den[qg*2+g2] += w0 + w1;
                    *(uint32_t*)&Wtb[cb][qr*132 + wv*16 + quad*4 + rp*2]
                        = pkbf16(w0, w1);
                }
            }
        }

        if (c + 1 < 32){
            const bf16_t* kr = xkb + (size_t)((c+1)*128 + wv*16 + col)*PAUG + quad*8;
            kf0 = ldb8(kr); kf1 = ldb8(kr + 32);
        }

        asm volatile("s_waitcnt lgkmcnt(0)" ::: "memory");
        __builtin_amdgcn_s_barrier();
        __builtin_amdgcn_sched_barrier(0);

        #pragma unroll
        for (int qg = 0; qg < 2; qg++){
            #pragma unroll
            for (int sk4 = 0; sk4 < 2; sk4++){
                bf16x8 af[4];
                #pragma unroll
                for (int j = 0; j < 4; j++)
                    af[j] = ldb8u(&Wtb[cb][(qg*32 + l31)*132 + (sk4*4 + j)*16 + half*8]);
                #pragma unroll
                for (int j = 0; j < 4; j++)
                    acc[qg] = MFMA32(af[j], vr[sk4*4 + j], acc[qg]);
            }
        }
    }

    // ---- den reduce ----
    #pragma unroll
    for (int d = 0; d < 4; d++){
        den[d] += __shfl_xor(den[d], 16);
        den[d] += __shfl_xor(den[d], 32);
    }
    if (lane < 16){
        #pragma unroll
        for (int qg = 0; qg < 2; qg++)
            #pragma unroll
            for (int g2 = 0; g2 < 2; g2++)
                densh[wv][qg*32 + g2*16 + lane] = den[qg*2+g2];
    }
    __syncthreads();
    if (tid < 64){
        float s = 0.f;
        #pragma unroll
        for (int w = 0; w < 8; w++) s += densh[w][tid];
        dent[tid] = 1.f / s;
    }
    __syncthreads();

    // ---- O -> LDS (write-side XOR piece swizzle: piece g at g^(row&7)) ----
    #pragma unroll
    for (int qg = 0; qg < 2; qg++){
        #pragma unroll
        for (int rg = 0; rg < 16; rg++){
            int qrow = qg*32 + (rg & 3) + 8*(rg >> 2) + 4*half;
            int e = wv*32 + l31;
            int g = e >> 3;
            Osh[qrow*256 + ((g ^ (qrow & 7))*8) + (e & 7)] = f2b(acc[qg][rg] * dent[qrow]);
        }
    }
    __syncthreads();

    // ---- y1 = O @ Wo^T : wave wv -> n-slice [wv*32, wv*32+32), K=256 ----
    v4f y[4][2];
    #pragma unroll
    for (int qg = 0; qg < 4; qg++)
        #pragma unroll
        for (int t = 0; t < 2; t++) y[qg][t] = (v4f){0.f,0.f,0.f,0.f};

    #pragma unroll
    for (int kc = 0; kc < 8; kc++){
        bf16x8 b0 = ldb8(wof + (size_t)(((wv*2+0)*8 + kc)*64 + lane)*8);
        bf16x8 b1 = ldb8(wof + (size_t)(((wv*2+1)*8 + kc)*64 + lane)*8);
        #pragma unroll
        for (int qg = 0; qg < 4; qg++){
            bf16x8 a = ldb8(&Osh[(qg*16 + col)*256 + (((kc*4 + quad) ^ (col & 7))*8)]);
            y[qg][0] = MFMA16(a, b0, y[qg][0]);
            y[qg][1] = MFMA16(a, b1, y[qg][1]);
        }
    }

    // ---- bias + residual + LN1 partials ----
    size_t growb = (size_t)b*SN + q0;
    float bo0 = bo[wv*32 + col], bo1 = bo[wv*32 + 16 + col];
    #pragma unroll
    for (int qg = 0; qg < 4; qg++){
        #pragma unroll
        for (int r = 0; r < 4; r++){
            int row = qg*16 + quad*4 + r;
            float x0 = y[qg][0][r] + bo0 + b2f(res[(growb + row)*EN + wv*32 + col]);
            float x1 = y[qg][1][r] + bo1 + b2f(res[(growb + row)*EN + wv*32 + 16 + col]);
            y[qg][0][r] = x0; y[qg][1][r] = x1;
            float s1 = x0 + x1, s2 = x0*x0 + x1*x1;
            #pragma unroll
            for (int m = 1; m <= 8; m <<= 1){
                s1 += __shfl_xor(s1, m);
                s2 += __shfl_xor(s2, m);
            }
            if (col == 0){
                lnw[wv][row][0] = s1;
                lnw[wv][row][1] = s2;
            }
        }
    }
    __syncthreads();

    // ---- LN1 finalize + store ----
    float g0 = gamma[wv*32 + col],      g1v = gamma[wv*32 + 16 + col];
    float e0 = beta[wv*32 + col],       e1v = beta[wv*32 + 16 + col];
    #pragma unroll
    for (int qg = 0; qg < 4; qg++){
        #pragma unroll
        for (int r = 0; r < 4; r++){
            int row = qg*16 + quad*4 + r;
            float S1 = 0.f, S2 = 0.f;
            #pragma unroll
            for (int w = 0; w < 8; w++){ S1 += lnw[w][row][0]; S2 += lnw[w][row][1]; }
            float mu = S1 * (1.f/256.f);
            float rs = rsqrtf(S2 * (1.f/256.f) - mu*mu + 1e-5f);
            out[(growb + row)*EN + wv*32 + col]      = f2b((y[qg][0][r]-mu)*rs*g0 + e0);
            out[(growb + row)*EN + wv*32 + 16 + col] = f2b((y[qg][1][r]-mu)*rs*g1v + e1v);
        }
    }
}

// ---------------------------------------------------------------------------
extern "C" void kernel_launch(void* const* d_in, const int* in_sizes, int n_in,
                              void* d_out, int out_size, void* d_ws, size_t ws_size,
                              hipStream_t stream)
{
    (void)in_sizes; (void)n_in; (void)out_size; (void)ws_size;
    const float* src  = (const float*)d_in[0];
    const float* pos  = (const float*)d_in[1];
    const float* Wpos = (const float*)d_in[2];
    const float* bpos = (const float*)d_in[3];
    const float* ls   = (const float*)d_in[4];
    const float* os   = (const float*)d_in[5];
    const float* Wv   = (const float*)d_in[6];
    const float* bv   = (const float*)d_in[7];
    const float* Wo   = (const float*)d_in[8];
    const float* bo   = (const float*)d_in[9];
    const float* W1   = (const float*)d_in[10];
    const float* b1   = (const float*)d_in[11];
    const float* W2   = (const float*)d_in[12];
    const float* b2   = (const float*)d_in[13];
    const float* g1   = (const float*)d_in[14];
    const float* be1  = (const float*)d_in[15];
    const float* g2   = (const float*)d_in[16];
    const float* be2  = (const float*)d_in[17];

    char* w = (char*)d_ws;
    bf16_t* xkb  = (bf16_t*)(w);                         // 2 MB [B,S,64]
    bf16_t* xqb  = (bf16_t*)(w + ( 2u<<20));             // 2 MB
    bf16_t* Wvb  = (bf16_t*)(w + ( 4u<<20));             // 128 KB
    bf16_t* Wob  = (bf16_t*)(w + ( 4u<<20) + (1u<<18));  // 128 KB (fragment order)
    bf16_t* W1b  = (bf16_t*)(w + ( 5u<<20));             // 512 KB
    bf16_t* W2b  = (bf16_t*)(w + ( 6u<<20));             // 512 KB
    bf16_t* srcb = (bf16_t*)(w + ( 8u<<20));             // 8 MB (alive thru attn res)
    bf16_t* vtg  = (bf16_t*)(w + (16u<<20));             // 8 MB vfrag
    bf16_t* xws  = (bf16_t*)(w + (24u<<20));             // 8 MB (x = LN1 out)
    bf16_t* hws  = (bf16_t*)(w + (32u<<20));             // 32 MB

    prep_kernel<<<dim3(4800), 256, 0, stream>>>(
        src, srcb, Wv, Wvb, Wo, Wob, W1, W1b, W2, W2b,
        pos, Wpos, bpos, ls, xkb, xqb);

    // v = src @ Wv^T + bv  -> fragment-ordered store vfrag[b][eb][k16][lane][8]
    gemm_t<3, bf16_t><<<dim3(BS/64, EN/64), 256, 0, stream>>>(
        srcb, Wvb, bv, (bf16_t*)nullptr, vtg, EN, EN);
    // x = LN1( softmax(..) @ v @ Wo^T + bo + src )   [attn + Wo + LN1 fused]
    attn_kernel<<<dim3(256), 512, 0, stream>>>(
        xkb, xqb, vtg, os, Wob, bo, srcb, g1, be1, xws);
    // h = relu(x @ W1^T + b1)
    gemm128<1><<<dim3(BS/128, FN/128), 256, 0, stream>>>(
        xws, W1b, b1, hws, FN, EN);
    // out = LN2(h @ W2^T + b2 + x) -> fp32  [fused gemm+LN]
    gemm_ln<float><<<dim3(BS/32), 512, 0, stream>>>(
        hws, W2b, b2, xws, g2, be2, (float*)d_out, FN);
}

// Round 10
// 225.626 us; speedup vs baseline: 1.1031x; 1.0278x over previous
//
#include <hip/hip_runtime.h>
#include <stdint.h>

#define BN 4
#define SN 4096
#define EN 256
#define PN 32
#define FN 1024
#define BS (BN*SN)   // 16384
#define PAUG 64      // 32 xs chans + aug (+ zero pad to 64)

typedef uint16_t bf16_t;
typedef short v4s  __attribute__((ext_vector_type(4)));
typedef short v8s  __attribute__((ext_vector_type(8)));
typedef __bf16 bf16x8 __attribute__((ext_vector_type(8)));
typedef float v4f   __attribute__((ext_vector_type(4)));
typedef float v16f  __attribute__((ext_vector_type(16)));

#define MFMA16(a,b,c) __builtin_amdgcn_mfma_f32_16x16x32_bf16(a,b,c,0,0,0)
#define MFMA32(a,b,c) __builtin_amdgcn_mfma_f32_32x32x16_bf16(a,b,c,0,0,0)

__device__ __forceinline__ float b2f(bf16_t x){
    uint32_t u = ((uint32_t)x) << 16; float f; __builtin_memcpy(&f, &u, 4); return f;
}
__device__ __forceinline__ bf16_t f2b(float f){
    uint32_t u; __builtin_memcpy(&u, &f, 4);
    u += 0x7FFFu + ((u >> 16) & 1u);           // RNE
    return (bf16_t)(u >> 16);
}
__device__ __forceinline__ bf16x8 ldb8(const bf16_t* p){
    v8s r = *(const v8s*)p; return __builtin_bit_cast(bf16x8, r);
}
// 8-B-aligned load pair (for LDS rows with odd 8-B stride -> 2-way-free banks)
__device__ __forceinline__ bf16x8 ldb8u(const bf16_t* p){
    v4s lo = *(const v4s*)p;
    v4s hi = *(const v4s*)(p + 4);
    v8s r = __builtin_shufflevector(lo, hi, 0,1,2,3,4,5,6,7);
    return __builtin_bit_cast(bf16x8, r);
}
__device__ __forceinline__ float ldsc(const float* p){ return *p; }
__device__ __forceinline__ float ldsc(const bf16_t* p){ return b2f(*p); }
__device__ __forceinline__ void stsc(float* p, float v){ *p = v; }
__device__ __forceinline__ void stsc(bf16_t* p, float v){ *p = f2b(v); }

#if __has_builtin(__builtin_amdgcn_exp2f)
__device__ __forceinline__ float fexp2(float x){ return __builtin_amdgcn_exp2f(x); }
#else
__device__ __forceinline__ float fexp2(float x){ return exp2f(x); }
#endif

#if __has_builtin(__builtin_amdgcn_cvt_pk_bf16_f32)
typedef __bf16 bf16x2 __attribute__((ext_vector_type(2)));
__device__ __forceinline__ uint32_t pkbf16(float a, float b){
    bf16x2 r = __builtin_amdgcn_cvt_pk_bf16_f32(a, b);
    return __builtin_bit_cast(uint32_t, r);
}
#else
__device__ __forceinline__ uint32_t pkbf16(float a, float b){
    return (uint32_t)f2b(a) | ((uint32_t)f2b(b) << 16);
}
#endif

typedef const __attribute__((address_space(1))) uint32_t* glds_gp;
typedef __attribute__((address_space(3))) uint32_t* glds_lp;
__device__ __forceinline__ void glds16(const bf16_t* g, bf16_t* l){
    __builtin_amdgcn_global_load_lds((glds_gp)g, (glds_lp)l, 16, 0, 0);
}

// ---------------------------------------------------------------------------
// prep: (a) src fp32->bf16, (b) weight cvts (Wo -> MFMA16-B FRAGMENT order),
// (c) posxs. One launch.
// ---------------------------------------------------------------------------
__global__ __launch_bounds__(256) void prep_kernel(
    const float* __restrict__ src, bf16_t* __restrict__ srcb,
    const float* __restrict__ Wv, bf16_t* __restrict__ Wvb,
    const float* __restrict__ Wo, bf16_t* __restrict__ Wob,
    const float* __restrict__ W1, bf16_t* __restrict__ W1b,
    const float* __restrict__ W2, bf16_t* __restrict__ W2b,
    const float* __restrict__ pos, const float* __restrict__ Wp,
    const float* __restrict__ bp,  const float* __restrict__ lsp,
    bf16_t* __restrict__ xk, bf16_t* __restrict__ xq)
{
    __shared__ float Wsh[PN*PN];
    __shared__ float bsh[PN];
    int bid = blockIdx.x;
    int tid = threadIdx.x;

    if (bid < 4736){
        const float* sp; bf16_t* dp; int off;
        if (bid < 4096){ sp = src; dp = srcb; off = (bid*256 + tid)*4; }
        else {
            int i = ((bid - 4096)*256 + tid)*4;
            if      (i <  65536){ sp=Wv; dp=Wvb; off=i; }
            else if (i < 131072){
                // Wo -> fragment order
                int idx = i - 65536;
                float4 f = *(const float4*)(Wo + idx);
                v4s o;
                o.x = (short)f2b(f.x); o.y = (short)f2b(f.y);
                o.z = (short)f2b(f.z); o.w = (short)f2b(f.w);
                int n = idx >> 8, k = idx & 255;
                int dst = (((n>>4)*8 + (k>>5))*64 + (((k>>3)&3)*16 + (n&15)))*8 + (k&7);
                *(v4s*)(Wob + dst) = o;
                return;
            }
            else if (i < 393216){ sp=W1; dp=W1b; off=i-131072; }
            else                { sp=W2; dp=W2b; off=i-393216; }
        }
        float4 f = *(const float4*)(sp + off);
        v4s o;
        o.x = (short)f2b(f.x); o.y = (short)f2b(f.y);
        o.z = (short)f2b(f.z); o.w = (short)f2b(f.w);
        *(v4s*)(dp + off) = o;
        return;
    }

    int pb = bid - 4736;          // 0..63
    int b  = pb >> 4;
    int s  = (pb & 15)*256 + tid;

    for (int i = tid; i < PN*PN; i += 256) Wsh[i] = Wp[i];
    if (tid < PN) bsh[tid] = bp[tid];
    __syncthreads();

    float inv_ls = 1.0f / lsp[0];
    const float c1f = 1.4426950408889634f;

    float col[PN];
    #pragma unroll
    for (int p = 0; p < PN; p++) col[p] = pos[((size_t)b*PN + p)*SN + s];

    uint16_t xb[PN], qb[PN];
    float sq = 0.f;
    #pragma unroll 4
    for (int o = 0; o < PN; o++){
        float pe = bsh[o];
        #pragma unroll
        for (int p = 0; p < PN; p++) pe += col[p] * Wsh[o*PN + p];
        float pv = pe * inv_ls;
        uint16_t h = f2b(pv);
        xb[o] = h;
        qb[o] = f2b(c1f * pv);
        float xr = b2f(h);
        sq += xr * xr;
    }

    size_t base = ((size_t)b*SN + s) * PAUG;
    v8s pk[8];
    #pragma unroll
    for (int c = 0; c < 4; c++)
        #pragma unroll
        for (int j = 0; j < 8; j++) ((short*)&pk[c])[j] = (short)xb[c*8 + j];
    #pragma unroll
    for (int c = 4; c < 8; c++)
        #pragma unroll
        for (int j = 0; j < 8; j++) ((short*)&pk[c])[j] = 0;
    ((short*)&pk[4])[0] = (short)f2b(-0.5f * sq);
    ((short*)&pk[4])[1] = (short)0x3F80;   // 1.0
    #pragma unroll
    for (int c = 0; c < 8; c++) *(v8s*)(xk + base + c*8) = pk[c];

    #pragma unroll
    for (int c = 0; c < 4; c++)
        #pragma unroll
        for (int j = 0; j < 8; j++) ((short*)&pk[c])[j] = (short)qb[c*8 + j];
    ((short*)&pk[4])[0] = (short)f2b(c1f);
    ((short*)&pk[4])[1] = (short)f2b(-0.5f * sq * c1f);
    #pragma unroll
    for (int c = 0; c < 8; c++) *(v8s*)(xq + base + c*8) = pk[c];
}

// ---------------------------------------------------------------------------
// gemm_t (64x64 tile) -- kept ONLY for the Wv projection (EPI 3: fragment-
// ordered V store for attn).
// ---------------------------------------------------------------------------
template<int EPI, typename OutT>
__global__ __launch_bounds__(256) void gemm_t(
    const bf16_t* __restrict__ A, const bf16_t* __restrict__ W,
    const float* __restrict__ bias, OutT* __restrict__ out,
    bf16_t* __restrict__ vt, int N, int K)
{
    __shared__ __align__(16) bf16_t At[2][4096];   // 2 x 8 KB
    __shared__ __align__(16) bf16_t Wt[2][4096];   // 2 x 8 KB
    int tid = threadIdx.x;
    int lane = tid & 63, wv = tid >> 6, col = lane & 15, quad = lane >> 4;
    int m0 = blockIdx.x * 64, n0 = blockIdx.y * 64;
    int nck = K >> 6;

    int srow = tid >> 3;                      // 0..31
    int spc  = (tid & 7) ^ (srow & 7);        // swizzled source piece
    const bf16_t* asrc = A + (size_t)(m0 + srow)*K + spc*8;
    const bf16_t* wsrc = W + (size_t)(n0 + srow)*K + spc*8;

    v4f acc[4];
    #pragma unroll
    for (int t = 0; t < 4; t++) acc[t] = (v4f){0.f,0.f,0.f,0.f};

    // stage chunk 0
    glds16(asrc, &At[0][tid*8]);
    glds16(asrc + (size_t)32*K, &At[0][2048 + tid*8]);
    glds16(wsrc, &Wt[0][tid*8]);
    glds16(wsrc + (size_t)32*K, &Wt[0][2048 + tid*8]);
    __syncthreads();

    for (int c = 0; c < nck; c++){
        int cb = c & 1;
        if (c + 1 < nck){
            glds16(asrc + (c+1)*64, &At[cb^1][tid*8]);
            glds16(asrc + (size_t)32*K + (c+1)*64, &At[cb^1][2048 + tid*8]);
            glds16(wsrc + (c+1)*64, &Wt[cb^1][tid*8]);
            glds16(wsrc + (size_t)32*K + (c+1)*64, &Wt[cb^1][2048 + tid*8]);
        }
        #pragma unroll
        for (int kc = 0; kc < 2; kc++){
            int pc = ((kc*4 + quad) ^ (col & 7)) * 8;
            bf16x8 a = ldb8(&At[cb][(wv*16 + col)*64 + pc]);
            #pragma unroll
            for (int t = 0; t < 4; t++){
                bf16x8 b = ldb8(&Wt[cb][(t*16 + col)*64 + pc]);
                acc[t] = MFMA16(a, b, acc[t]);
            }
        }
        __syncthreads();
    }

    float bfv[4];
    #pragma unroll
    for (int t = 0; t < 4; t++) bfv[t] = bias[n0 + t*16 + col];

    if constexpr (EPI == 3){
        __shared__ uint16_t Tsh[64*74];
        #pragma unroll
        for (int r = 0; r < 4; r++)
            #pragma unroll
            for (int t = 0; t < 4; t++)
                Tsh[(wv*16 + quad*4 + r)*74 + t*16 + col] = f2b(acc[t][r] + bfv[t]);
        __syncthreads();
        int e = tid >> 2, sc = tid & 3;
        int b = m0 >> 12;
        int sbat = m0 & (SN-1);
        int eb   = (n0 + e) >> 5;
        int l31e = (n0 + e) & 31;
        int k16  = (sbat >> 4) + sc;
        v8s p0, p1;
        #pragma unroll
        for (int i = 0; i < 8; i++) ((short*)&p0)[i] = (short)Tsh[(sc*16 + i)*74 + e];
        #pragma unroll
        for (int i = 0; i < 8; i++) ((short*)&p1)[i] = (short)Tsh[(sc*16 + 8 + i)*74 + e];
        bf16_t* dst = vt + ((((size_t)b*8 + eb)*256 + k16)*64 + l31e)*8;
        *(v8s*)dst = p0;              // half 0 (keys s&15 in 0..7)
        *(v8s*)(dst + 256) = p1;      // half 1 (keys s&15 in 8..15), +32 lanes
    } else {
        #pragma unroll
        for (int r = 0; r < 4; r++){
            int row = m0 + wv*16 + quad*4 + r;
            #pragma unroll
            for (int t = 0; t < 4; t++){
                float y = acc[t][r] + bfv[t];
                if constexpr (EPI == 1) y = fmaxf(y, 0.f);
                stsc(out + (size_t)row*N + n0 + t*16 + col, y);
            }
        }
    }
}

// ---------------------------------------------------------------------------
// ffn_ln: out = LN2( relu(x @ W1^T + b1) @ W2^T + b2 + x ) -> fp32.
// 64 rows/block, grid 256, 512 thr = 8 waves as 4m x 2n.
// 16 chunks of 64 h-cols. Per chunk: stage W1-slice (64h x 256k, 32 KB) +
// W2-slice (256n x 64k, 32 KB) parity-double-buffered via glds16 with
// COUNTED vmcnt(8) (next chunk's stage stays in flight across the barrier);
// gemm1 (x-regs @ W1c) -> relu -> Hs (stride 68, 2-way-free) -> raw barrier;
// gemm2 (Hs @ W2c) accumulates y2[64][256]; raw end barrier. x kept in
// registers as A-fragments (loaded once). LN2 fused gemm_ln-style.
// LDS ~142 KB -> 1 block/CU (grid 256 = exactly one round).
// ---------------------------------------------------------------------------
__global__ __launch_bounds__(512) void ffn_ln_kernel(
    const bf16_t* __restrict__ x,  const bf16_t* __restrict__ W1b,
    const float* __restrict__ b1,  const bf16_t* __restrict__ W2b,
    const float* __restrict__ b2,  const float* __restrict__ gamma,
    const float* __restrict__ beta, float* __restrict__ out)
{
    __shared__ __align__(16) bf16_t W1c[2][16384];  // 2 x 32 KB [s][wr][p]
    __shared__ __align__(16) bf16_t W2c[2][16384];  // 2 x 32 KB [s2][wr2][p]
    __shared__ __align__(16) bf16_t Hs[64*68];      // 8.5 KB
    __shared__ float b1sh[1024];                    // 4 KB
    __shared__ float lnb[2][64][2];                 // 1 KB

    int tid  = threadIdx.x;
    int lane = tid & 63;
    int wv   = tid >> 6;         // 0..7
    int col  = lane & 15;
    int quad = lane >> 4;
    int mw   = wv >> 1;          // 0..3 -> rows mw*16..+16
    int nw   = wv & 1;           // 0..1
    int m0   = blockIdx.x * 64;

    b1sh[tid]       = b1[tid];
    b1sh[512 + tid] = b1[512 + tid];

    // x A-fragments in registers: row = m0 + mw*16 + col, k = kk*32+quad*8
    const bf16_t* xrow = x + (size_t)(m0 + mw*16 + col)*EN + quad*8;
    bf16x8 xr[8];
    #pragma unroll
    for (int kk = 0; kk < 8; kk++) xr[kk] = ldb8(xrow + kk*32);

    // epilogue constants: n = nw*128 + t2*16 + col
    float b2v[8], gv[8], bev[8];
    #pragma unroll
    for (int t2 = 0; t2 < 8; t2++){
        int nn = nw*128 + t2*16 + col;
        b2v[t2] = b2[nn]; gv[t2] = gamma[nn]; bev[t2] = beta[nn];
    }

    v4f acc[8];
    #pragma unroll
    for (int t2 = 0; t2 < 8; t2++) acc[t2] = (v4f){0.f,0.f,0.f,0.f};

    int wr  = tid >> 3;          // 0..63
    int pp  = tid & 7;
    int swz = (pp ^ (wr & 7)) * 8;

    // prologue: stage chunk 0 into parity 0 (8 glds16/thread)
    #pragma unroll
    for (int s = 0; s < 4; s++)
        glds16(W1b + (size_t)wr*256 + s*64 + swz, &W1c[0][s*4096 + tid*8]);
    #pragma unroll
    for (int s2 = 0; s2 < 4; s2++)
        glds16(W2b + (size_t)(s2*64 + wr)*1024 + swz, &W2c[0][s2*4096 + tid*8]);

    #pragma unroll 1
    for (int c = 0; c < 16; c++){
        int par = c & 1;
        if (c < 15){
            // stage chunk c+1 into parity^1 (stays in flight past the barrier)
            #pragma unroll
            for (int s = 0; s < 4; s++)
                glds16(W1b + (size_t)((c+1)*64 + wr)*256 + s*64 + swz,
                       &W1c[par^1][s*4096 + tid*8]);
            #pragma unroll
            for (int s2 = 0; s2 < 4; s2++)
                glds16(W2b + (size_t)(s2*64 + wr)*1024 + (c+1)*64 + swz,
                       &W2c[par^1][s2*4096 + tid*8]);
            asm volatile("s_waitcnt vmcnt(8)" ::: "memory");   // drain chunk c only
        } else {
            asm volatile("s_waitcnt vmcnt(0)" ::: "memory");
        }
        __builtin_amdgcn_s_barrier();
        __builtin_amdgcn_sched_barrier(0);

        // gemm1: h[64][64] = relu(x @ W1c^T + b1c); wave: rows mw*16, h-cols nw*32
        v4f hacc[2];
        hacc[0] = (v4f){0.f,0.f,0.f,0.f};
        hacc[1] = (v4f){0.f,0.f,0.f,0.f};
        #pragma unroll
        for (int kk = 0; kk < 8; kk++){
            #pragma unroll
            for (int t = 0; t < 2; t++){
                int hl = nw*32 + t*16 + col;
                bf16x8 b = ldb8(&W1c[par][(kk>>1)*4096 + hl*64
                                 + ((((kk&1)*4 + quad) ^ (hl & 7))*8)]);
                hacc[t] = MFMA16(xr[kk], b, hacc[t]);
            }
        }
        #pragma unroll
        for (int t = 0; t < 2; t++){
            float bb = b1sh[c*64 + nw*32 + t*16 + col];
            #pragma unroll
            for (int r = 0; r < 4; r++){
                float h = fmaxf(hacc[t][r] + bb, 0.f);
                Hs[(mw*16 + quad*4 + r)*68 + nw*32 + t*16 + col] = f2b(h);
            }
        }
        asm volatile("s_waitcnt lgkmcnt(0)" ::: "memory");
        __builtin_amdgcn_s_barrier();
        __builtin_amdgcn_sched_barrier(0);

        // gemm2: y2 += Hs @ W2c^T; wave: rows mw*16, n-cols nw*128
        #pragma unroll
        for (int kk2 = 0; kk2 < 2; kk2++){
            bf16x8 a2 = ldb8u(&Hs[(mw*16 + col)*68 + kk2*32 + quad*8]);
            #pragma unroll
            for (int t2 = 0; t2 < 8; t2++){
                int nn = nw*128 + t2*16 + col;
                bf16x8 bfr = ldb8(&W2c[par][(nn>>6)*4096 + (nn&63)*64
                                  + ((((kk2*4 + quad) ^ (col & 7)))*8)]);
                acc[t2] = MFMA16(a2, bfr, acc[t2]);
            }
        }
        asm volatile("s_waitcnt lgkmcnt(0)" ::: "memory");
        __builtin_amdgcn_s_barrier();   // all reads of par + Hs done
    }

    // ---- fused LN2 epilogue ----
    float v[8][4];
    float s1[4], s2[4];
    #pragma unroll
    for (int r = 0; r < 4; r++){ s1[r] = 0.f; s2[r] = 0.f; }
    #pragma unroll
    for (int r = 0; r < 4; r++){
        int row = m0 + mw*16 + quad*4 + r;
        #pragma unroll
        for (int t2 = 0; t2 < 8; t2++){
            int nn = nw*128 + t2*16 + col;
            float xv = acc[t2][r] + b2v[t2] + b2f(x[(size_t)row*EN + nn]);
            v[t2][r] = xv; s1[r] += xv; s2[r] += xv*xv;
        }
    }
    #pragma unroll
    for (int r = 0; r < 4; r++){
        #pragma unroll
        for (int m = 1; m <= 8; m <<= 1){
            s1[r] += __shfl_xor(s1[r], m);
            s2[r] += __shfl_xor(s2[r], m);
        }
    }
    if (col == 0){
        #pragma unroll
        for (int r = 0; r < 4; r++){
            int rl = mw*16 + quad*4 + r;
            lnb[nw][rl][0] = s1[r];
            lnb[nw][rl][1] = s2[r];
        }
    }
    __syncthreads();
    #pragma unroll
    for (int r = 0; r < 4; r++){
        int rl  = mw*16 + quad*4 + r;
        int row = m0 + rl;
        float S1 = lnb[0][rl][0] + lnb[1][rl][0];
        float S2 = lnb[0][rl][1] + lnb[1][rl][1];
        float mu = S1 * (1.f/256.f);
        float rs = rsqrtf(S2 * (1.f/256.f) - mu*mu + 1e-5f);
        #pragma unroll
        for (int t2 = 0; t2 < 8; t2++){
            int nn = nw*128 + t2*16 + col;
            out[(size_t)row*EN + nn] = (v[t2][r] - mu)*rs*gv[t2] + bev[t2];
        }
    }
}

// ---------------------------------------------------------------------------
// Attention round 18: chunk = 256 keys (16 chunks, HALF the barriers of
// round 9), vr[16], Wtb stride 260 (round-3-verified layout), raw barrier
// (no vmcnt drain), parity dbuf. Fused Wo+res+LN1 epilogue (round-9-verified).
// ---------------------------------------------------------------------------
__global__ __launch_bounds__(512, 2) void attn_kernel(
    const bf16_t* __restrict__ xk, const bf16_t* __restrict__ xq,
    const bf16_t* __restrict__ vf, const float* __restrict__ osp,
    const bf16_t* __restrict__ wof, const float* __restrict__ bo,
    const bf16_t* __restrict__ res, const float* __restrict__ gamma,
    const float* __restrict__ beta, bf16_t* __restrict__ out)
{
    __shared__ __align__(16) bf16_t Wtb[2][64*260];   // 65 KB
    __shared__ __align__(16) bf16_t Qs[64*64];        // 8 KB
    __shared__ __align__(16) bf16_t Osh[64*256];      // 32 KB (O tile, swizzled)
    __shared__ float densh[8][64];                    // 2 KB
    __shared__ float dent[64];
    __shared__ float lnw[8][64][2];                   // 4 KB

    int tid  = threadIdx.x;
    int lane = tid & 63;
    int wv   = tid >> 6;          // 0..7
    int col  = lane & 15;
    int quad = lane >> 4;
    int l31  = lane & 31;
    int half = lane >> 5;

    int bid = blockIdx.x;                    // 0..255
    int b   = (bid & 7) >> 1;
    int qi  = ((bid >> 3) << 1) | (bid & 1); // 0..63
    int q0  = qi * 64;

    float k2 = 1.4426950408889634f * osp[0];

    const bf16_t* xkb = xk + (size_t)b * SN * PAUG;
    const bf16_t* xqb = xq + (size_t)b * SN * PAUG;
    const bf16_t* vfb = vf + (((size_t)b*8 + wv)*256)*512 + lane*8;

    // stage Q tile: piece-swizzled SOURCE, linear dest
    {
        int qrow = tid >> 3;                 // 0..63
        int qpc  = (tid & 7) ^ (qrow & 7);
        glds16(xqb + (size_t)(q0 + qrow)*PAUG + qpc*8, &Qs[tid*8]);
    }

    v16f acc[2];
    #pragma unroll
    for (int qg = 0; qg < 2; qg++)
        #pragma unroll
        for (int i = 0; i < 16; i++) acc[qg][i] = 0.f;
    float den[4] = {0.f, 0.f, 0.f, 0.f};
    const v4f zero = (v4f){0.f,0.f,0.f,0.f};

    // kf prologue (chunk 0): this wave's 32 keys, 2 kg x 2 paug-halves
    bf16x8 kf[2][2];
    #pragma unroll
    for (int kg = 0; kg < 2; kg++)
        #pragma unroll
        for (int h = 0; h < 2; h++)
            kf[kg][h] = ldb8(xkb + (size_t)(wv*32 + kg*16 + col)*PAUG + h*32 + quad*8);

    __syncthreads();   // Qs staged

    for (int c = 0; c < 16; c++){
        int cb = c & 1;
        // issue V(c): 16 coalesced b128 into regs
        bf16x8 vr[16];
        #pragma unroll
        for (int sk = 0; sk < 16; sk++)
            vr[sk] = ldb8(vfb + (size_t)(c*16 + sk)*512);

        // QK + exp: this wave's 32-key slice x 64 q of chunk c
        #pragma unroll
        for (int qg = 0; qg < 2; qg++){
            #pragma unroll
            for (int g2 = 0; g2 < 2; g2++){
                int qr = qg*32 + g2*16 + col;
                bf16x8 qa = ldb8(&Qs[qr*64 + ((quad    ) ^ (col & 7))*8]);
                bf16x8 qb = ldb8(&Qs[qr*64 + ((4 + quad) ^ (col & 7))*8]);
                #pragma unroll
                for (int kg = 0; kg < 2; kg++){
                    v4f st = MFMA16(kf[kg][0], qa, zero);
                    st = MFMA16(kf[kg][1], qb, st);
                    #pragma unroll
                    for (int rp = 0; rp < 2; rp++){
                        float w0 = fexp2(fmaf(k2, fexp2(st[rp*2+0]), -k2));
                        float w1 = fexp2(fmaf(k2, fexp2(st[rp*2+1]), -k2));
                        den[qg*2+g2] += w0 + w1;
                        *(uint32_t*)&Wtb[cb][qr*260 + wv*32 + kg*16 + quad*4 + rp*2]
                            = pkbf16(w0, w1);
                    }
                }
            }
        }

        // prefetch kf(c+1) (stays in flight across raw barrier)
        if (c + 1 < 16){
            #pragma unroll
            for (int kg = 0; kg < 2; kg++)
                #pragma unroll
                for (int h = 0; h < 2; h++)
                    kf[kg][h] = ldb8(xkb + (size_t)((c+1)*256 + wv*32 + kg*16 + col)*PAUG
                                     + h*32 + quad*8);
        }

        asm volatile("s_waitcnt lgkmcnt(0)" ::: "memory");
        __builtin_amdgcn_s_barrier();
        __builtin_amdgcn_sched_barrier(0);

        // PV chunk c: this wave's 32-e slice, 2 qg x 16 MFMA32 over k=256
        #pragma unroll
        for (int qg = 0; qg < 2; qg++){
            #pragma unroll
            for (int sk4 = 0; sk4 < 4; sk4++){
                bf16x8 af[4];
                #pragma unroll
                for (int j = 0; j < 4; j++)
                    af[j] = ldb8u(&Wtb[cb][(qg*32 + l31)*260 + (sk4*4 + j)*16 + half*8]);
                #pragma unroll
                for (int j = 0; j < 4; j++)
                    acc[qg] = MFMA32(af[j], vr[sk4*4 + j], acc[qg]);
            }
        }
    }

    // ---- den reduce ----
    #pragma unroll
    for (int d = 0; d < 4; d++){
        den[d] += __shfl_xor(den[d], 16);
        den[d] += __shfl_xor(den[d], 32);
    }
    if (lane < 16){
        #pragma unroll
        for (int qg = 0; qg < 2; qg++)
            #pragma unroll
            for (int g2 = 0; g2 < 2; g2++)
                densh[wv][qg*32 + g2*16 + lane] = den[qg*2+g2];
    }
    __syncthreads();
    if (tid < 64){
        float s = 0.f;
        #pragma unroll
        for (int w = 0; w < 8; w++) s += densh[w][tid];
        dent[tid] = 1.f / s;
    }
    __syncthreads();

    // ---- O -> LDS (write-side XOR piece swizzle) ----
    #pragma unroll
    for (int qg = 0; qg < 2; qg++){
        #pragma unroll
        for (int rg = 0; rg < 16; rg++){
            int qrow = qg*32 + (rg & 3) + 8*(rg >> 2) + 4*half;
            int e = wv*32 + l31;
            int g = e >> 3;
            Osh[qrow*256 + ((g ^ (qrow & 7))*8) + (e & 7)] = f2b(acc[qg][rg] * dent[qrow]);
        }
    }
    __syncthreads();

    // ---- y1 = O @ Wo^T : wave wv -> n-slice [wv*32, wv*32+32), K=256 ----
    v4f y[4][2];
    #pragma unroll
    for (int qg = 0; qg < 4; qg++)
        #pragma unroll
        for (int t = 0; t < 2; t++) y[qg][t] = (v4f){0.f,0.f,0.f,0.f};

    #pragma unroll
    for (int kc = 0; kc < 8; kc++){
        bf16x8 b0 = ldb8(wof + (size_t)(((wv*2+0)*8 + kc)*64 + lane)*8);
        bf16x8 b1 = ldb8(wof + (size_t)(((wv*2+1)*8 + kc)*64 + lane)*8);
        #pragma unroll
        for (int qg = 0; qg < 4; qg++){
            bf16x8 a = ldb8(&Osh[(qg*16 + col)*256 + (((kc*4 + quad) ^ (col & 7))*8)]);
            y[qg][0] = MFMA16(a, b0, y[qg][0]);
            y[qg][1] = MFMA16(a, b1, y[qg][1]);
        }
    }

    // ---- bias + residual + LN1 partials ----
    size_t growb = (size_t)b*SN + q0;
    float bo0 = bo[wv*32 + col], bo1 = bo[wv*32 + 16 + col];
    #pragma unroll
    for (int qg = 0; qg < 4; qg++){
        #pragma unroll
        for (int r = 0; r < 4; r++){
            int row = qg*16 + quad*4 + r;
            float x0 = y[qg][0][r] + bo0 + b2f(res[(growb + row)*EN + wv*32 + col]);
            float x1 = y[qg][1][r] + bo1 + b2f(res[(growb + row)*EN + wv*32 + 16 + col]);
            y[qg][0][r] = x0; y[qg][1][r] = x1;
            float s1 = x0 + x1, s2 = x0*x0 + x1*x1;
            #pragma unroll
            for (int m = 1; m <= 8; m <<= 1){
                s1 += __shfl_xor(s1, m);
                s2 += __shfl_xor(s2, m);
            }
            if (col == 0){
                lnw[wv][row][0] = s1;
                lnw[wv][row][1] = s2;
            }
        }
    }
    __syncthreads();

    // ---- LN1 finalize + store ----
    float g0 = gamma[wv*32 + col],      g1v = gamma[wv*32 + 16 + col];
    float e0 = beta[wv*32 + col],       e1v = beta[wv*32 + 16 + col];
    #pragma unroll
    for (int qg = 0; qg < 4; qg++){
        #pragma unroll
        for (int r = 0; r < 4; r++){
            int row = qg*16 + quad*4 + r;
            float S1 = 0.f, S2 = 0.f;
            #pragma unroll
            for (int w = 0; w < 8; w++){ S1 += lnw[w][row][0]; S2 += lnw[w][row][1]; }
            float mu = S1 * (1.f/256.f);
            float rs = rsqrtf(S2 * (1.f/256.f) - mu*mu + 1e-5f);
            out[(growb + row)*EN + wv*32 + col]      = f2b((y[qg][0][r]-mu)*rs*g0 + e0);
            out[(growb + row)*EN + wv*32 + 16 + col] = f2b((y[qg][1][r]-mu)*rs*g1v + e1v);
        }
    }
}

// ---------------------------------------------------------------------------
extern "C" void kernel_launch(void* const* d_in, const int* in_sizes, int n_in,
                              void* d_out, int out_size, void* d_ws, size_t ws_size,
                              hipStream_t stream)
{
    (void)in_sizes; (void)n_in; (void)out_size; (void)ws_size;
    const float* src  = (const float*)d_in[0];
    const float* pos  = (const float*)d_in[1];
    const float* Wpos = (const float*)d_in[2];
    const float* bpos = (const float*)d_in[3];
    const float* ls   = (const float*)d_in[4];
    const float* os   = (const float*)d_in[5];
    const float* Wv   = (const float*)d_in[6];
    const float* bv   = (const float*)d_in[7];
    const float* Wo   = (const float*)d_in[8];
    const float* bo   = (const float*)d_in[9];
    const float* W1   = (const float*)d_in[10];
    const float* b1   = (const float*)d_in[11];
    const float* W2   = (const float*)d_in[12];
    const float* b2   = (const float*)d_in[13];
    const float* g1   = (const float*)d_in[14];
    const float* be1  = (const float*)d_in[15];
    const float* g2   = (const float*)d_in[16];
    const float* be2  = (const float*)d_in[17];

    char* w = (char*)d_ws;
    bf16_t* xkb  = (bf16_t*)(w);                         // 2 MB [B,S,64]
    bf16_t* xqb  = (bf16_t*)(w + ( 2u<<20));             // 2 MB
    bf16_t* Wvb  = (bf16_t*)(w + ( 4u<<20));             // 128 KB
    bf16_t* Wob  = (bf16_t*)(w + ( 4u<<20) + (1u<<18));  // 128 KB (fragment order)
    bf16_t* W1b  = (bf16_t*)(w + ( 5u<<20));             // 512 KB
    bf16_t* W2b  = (bf16_t*)(w + ( 6u<<20));             // 512 KB
    bf16_t* srcb = (bf16_t*)(w + ( 8u<<20));             // 8 MB (alive thru attn res)
    bf16_t* vtg  = (bf16_t*)(w + (16u<<20));             // 8 MB vfrag
    bf16_t* xws  = (bf16_t*)(w + (24u<<20));             // 8 MB (x = LN1 out)

    prep_kernel<<<dim3(4800), 256, 0, stream>>>(
        src, srcb, Wv, Wvb, Wo, Wob, W1, W1b, W2, W2b,
        pos, Wpos, bpos, ls, xkb, xqb);

    // v = src @ Wv^T + bv  -> fragment-ordered store vfrag[b][eb][k16][lane][8]
    gemm_t<3, bf16_t><<<dim3(BS/64, EN/64), 256, 0, stream>>>(
        srcb, Wvb, bv, (bf16_t*)nullptr, vtg, EN, EN);
    // x = LN1( softmax(..) @ v @ Wo^T + bo + src )   [attn + Wo + LN1 fused]
    attn_kernel<<<dim3(256), 512, 0, stream>>>(
        xkb, xqb, vtg, os, Wob, bo, srcb, g1, be1, xws);
    // out = LN2( relu(x@W1^T+b1) @ W2^T + b2 + x )   [FFN + LN2 fused]
    ffn_ln_kernel<<<dim3(BS/64), 512, 0, stream>>>(
        xws, W1b, b1, W2b, b2, g2, be2, (float*)d_out);
}

// Round 11
// 224.100 us; speedup vs baseline: 1.1106x; 1.0068x over previous
//
#include <hip/hip_runtime.h>
#include <stdint.h>

#define BN 4
#define SN 4096
#define EN 256
#define PN 32
#define FN 1024
#define BS (BN*SN)   // 16384
#define PAUG 64      // 32 xs chans + aug (+ zero pad to 64)

typedef uint16_t bf16_t;
typedef short v4s  __attribute__((ext_vector_type(4)));
typedef short v8s  __attribute__((ext_vector_type(8)));
typedef __bf16 bf16x8 __attribute__((ext_vector_type(8)));
typedef float v4f   __attribute__((ext_vector_type(4)));
typedef float v16f  __attribute__((ext_vector_type(16)));

#define MFMA16(a,b,c) __builtin_amdgcn_mfma_f32_16x16x32_bf16(a,b,c,0,0,0)
#define MFMA32(a,b,c) __builtin_amdgcn_mfma_f32_32x32x16_bf16(a,b,c,0,0,0)

__device__ __forceinline__ float b2f(bf16_t x){
    uint32_t u = ((uint32_t)x) << 16; float f; __builtin_memcpy(&f, &u, 4); return f;
}
__device__ __forceinline__ bf16_t f2b(float f){
    uint32_t u; __builtin_memcpy(&u, &f, 4);
    u += 0x7FFFu + ((u >> 16) & 1u);           // RNE
    return (bf16_t)(u >> 16);
}
__device__ __forceinline__ bf16x8 ldb8(const bf16_t* p){
    v8s r = *(const v8s*)p; return __builtin_bit_cast(bf16x8, r);
}
// 8-B-aligned load pair (for LDS rows with odd 8-B stride -> 2-way-free banks)
__device__ __forceinline__ bf16x8 ldb8u(const bf16_t* p){
    v4s lo = *(const v4s*)p;
    v4s hi = *(const v4s*)(p + 4);
    v8s r = __builtin_shufflevector(lo, hi, 0,1,2,3,4,5,6,7);
    return __builtin_bit_cast(bf16x8, r);
}
__device__ __forceinline__ float ldsc(const float* p){ return *p; }
__device__ __forceinline__ float ldsc(const bf16_t* p){ return b2f(*p); }
__device__ __forceinline__ void stsc(float* p, float v){ *p = v; }
__device__ __forceinline__ void stsc(bf16_t* p, float v){ *p = f2b(v); }

#if __has_builtin(__builtin_amdgcn_exp2f)
__device__ __forceinline__ float fexp2(float x){ return __builtin_amdgcn_exp2f(x); }
#else
__device__ __forceinline__ float fexp2(float x){ return exp2f(x); }
#endif

#if __has_builtin(__builtin_amdgcn_cvt_pk_bf16_f32)
typedef __bf16 bf16x2 __attribute__((ext_vector_type(2)));
__device__ __forceinline__ uint32_t pkbf16(float a, float b){
    bf16x2 r = __builtin_amdgcn_cvt_pk_bf16_f32(a, b);
    return __builtin_bit_cast(uint32_t, r);
}
#else
__device__ __forceinline__ uint32_t pkbf16(float a, float b){
    return (uint32_t)f2b(a) | ((uint32_t)f2b(b) << 16);
}
#endif

typedef const __attribute__((address_space(1))) uint32_t* glds_gp;
typedef __attribute__((address_space(3))) uint32_t* glds_lp;
__device__ __forceinline__ void glds16(const bf16_t* g, bf16_t* l){
    __builtin_amdgcn_global_load_lds((glds_gp)g, (glds_lp)l, 16, 0, 0);
}

// ---------------------------------------------------------------------------
// prep: (a) src fp32->bf16, (b) weight cvts (Wo -> MFMA16-B FRAGMENT order),
// (c) posxs. One launch.
// ---------------------------------------------------------------------------
__global__ __launch_bounds__(256) void prep_kernel(
    const float* __restrict__ src, bf16_t* __restrict__ srcb,
    const float* __restrict__ Wv, bf16_t* __restrict__ Wvb,
    const float* __restrict__ Wo, bf16_t* __restrict__ Wob,
    const float* __restrict__ W1, bf16_t* __restrict__ W1b,
    const float* __restrict__ W2, bf16_t* __restrict__ W2b,
    const float* __restrict__ pos, const float* __restrict__ Wp,
    const float* __restrict__ bp,  const float* __restrict__ lsp,
    bf16_t* __restrict__ xk, bf16_t* __restrict__ xq)
{
    __shared__ float Wsh[PN*PN];
    __shared__ float bsh[PN];
    int bid = blockIdx.x;
    int tid = threadIdx.x;

    if (bid < 4736){
        const float* sp; bf16_t* dp; int off;
        if (bid < 4096){ sp = src; dp = srcb; off = (bid*256 + tid)*4; }
        else {
            int i = ((bid - 4096)*256 + tid)*4;
            if      (i <  65536){ sp=Wv; dp=Wvb; off=i; }
            else if (i < 131072){
                // Wo -> fragment order
                int idx = i - 65536;
                float4 f = *(const float4*)(Wo + idx);
                v4s o;
                o.x = (short)f2b(f.x); o.y = (short)f2b(f.y);
                o.z = (short)f2b(f.z); o.w = (short)f2b(f.w);
                int n = idx >> 8, k = idx & 255;
                int dst = (((n>>4)*8 + (k>>5))*64 + (((k>>3)&3)*16 + (n&15)))*8 + (k&7);
                *(v4s*)(Wob + dst) = o;
                return;
            }
            else if (i < 393216){ sp=W1; dp=W1b; off=i-131072; }
            else                { sp=W2; dp=W2b; off=i-393216; }
        }
        float4 f = *(const float4*)(sp + off);
        v4s o;
        o.x = (short)f2b(f.x); o.y = (short)f2b(f.y);
        o.z = (short)f2b(f.z); o.w = (short)f2b(f.w);
        *(v4s*)(dp + off) = o;
        return;
    }

    int pb = bid - 4736;          // 0..63
    int b  = pb >> 4;
    int s  = (pb & 15)*256 + tid;

    for (int i = tid; i < PN*PN; i += 256) Wsh[i] = Wp[i];
    if (tid < PN) bsh[tid] = bp[tid];
    __syncthreads();

    float inv_ls = 1.0f / lsp[0];
    const float c1f = 1.4426950408889634f;

    float col[PN];
    #pragma unroll
    for (int p = 0; p < PN; p++) col[p] = pos[((size_t)b*PN + p)*SN + s];

    uint16_t xb[PN], qb[PN];
    float sq = 0.f;
    #pragma unroll 4
    for (int o = 0; o < PN; o++){
        float pe = bsh[o];
        #pragma unroll
        for (int p = 0; p < PN; p++) pe += col[p] * Wsh[o*PN + p];
        float pv = pe * inv_ls;
        uint16_t h = f2b(pv);
        xb[o] = h;
        qb[o] = f2b(c1f * pv);
        float xr = b2f(h);
        sq += xr * xr;
    }

    size_t base = ((size_t)b*SN + s) * PAUG;
    v8s pk[8];
    #pragma unroll
    for (int c = 0; c < 4; c++)
        #pragma unroll
        for (int j = 0; j < 8; j++) ((short*)&pk[c])[j] = (short)xb[c*8 + j];
    #pragma unroll
    for (int c = 4; c < 8; c++)
        #pragma unroll
        for (int j = 0; j < 8; j++) ((short*)&pk[c])[j] = 0;
    ((short*)&pk[4])[0] = (short)f2b(-0.5f * sq);
    ((short*)&pk[4])[1] = (short)0x3F80;   // 1.0
    #pragma unroll
    for (int c = 0; c < 8; c++) *(v8s*)(xk + base + c*8) = pk[c];

    #pragma unroll
    for (int c = 0; c < 4; c++)
        #pragma unroll
        for (int j = 0; j < 8; j++) ((short*)&pk[c])[j] = (short)qb[c*8 + j];
    ((short*)&pk[4])[0] = (short)f2b(c1f);
    ((short*)&pk[4])[1] = (short)f2b(-0.5f * sq * c1f);
    #pragma unroll
    for (int c = 0; c < 8; c++) *(v8s*)(xq + base + c*8) = pk[c];
}

// ---------------------------------------------------------------------------
// gemm_t (64x64 tile) -- kept ONLY for the Wv projection (EPI 3: fragment-
// ordered V store). ROUND 11: epilogue thread map e=tid&63, sc=tid>>6 so
// consecutive lanes write consecutive vfrag lanes -> 512-B contiguous
// segments per store instr (was 16 B at 512-B stride = 4x write amp).
// ---------------------------------------------------------------------------
template<int EPI, typename OutT>
__global__ __launch_bounds__(256) void gemm_t(
    const bf16_t* __restrict__ A, const bf16_t* __restrict__ W,
    const float* __restrict__ bias, OutT* __restrict__ out,
    bf16_t* __restrict__ vt, int N, int K)
{
    __shared__ __align__(16) bf16_t At[2][4096];   // 2 x 8 KB
    __shared__ __align__(16) bf16_t Wt[2][4096];   // 2 x 8 KB
    int tid = threadIdx.x;
    int lane = tid & 63, wv = tid >> 6, col = lane & 15, quad = lane >> 4;
    int m0 = blockIdx.x * 64, n0 = blockIdx.y * 64;
    int nck = K >> 6;

    int srow = tid >> 3;                      // 0..31
    int spc  = (tid & 7) ^ (srow & 7);        // swizzled source piece
    const bf16_t* asrc = A + (size_t)(m0 + srow)*K + spc*8;
    const bf16_t* wsrc = W + (size_t)(n0 + srow)*K + spc*8;

    v4f acc[4];
    #pragma unroll
    for (int t = 0; t < 4; t++) acc[t] = (v4f){0.f,0.f,0.f,0.f};

    // stage chunk 0
    glds16(asrc, &At[0][tid*8]);
    glds16(asrc + (size_t)32*K, &At[0][2048 + tid*8]);
    glds16(wsrc, &Wt[0][tid*8]);
    glds16(wsrc + (size_t)32*K, &Wt[0][2048 + tid*8]);
    __syncthreads();

    for (int c = 0; c < nck; c++){
        int cb = c & 1;
        if (c + 1 < nck){
            glds16(asrc + (c+1)*64, &At[cb^1][tid*8]);
            glds16(asrc + (size_t)32*K + (c+1)*64, &At[cb^1][2048 + tid*8]);
            glds16(wsrc + (c+1)*64, &Wt[cb^1][tid*8]);
            glds16(wsrc + (size_t)32*K + (c+1)*64, &Wt[cb^1][2048 + tid*8]);
        }
        #pragma unroll
        for (int kc = 0; kc < 2; kc++){
            int pc = ((kc*4 + quad) ^ (col & 7)) * 8;
            bf16x8 a = ldb8(&At[cb][(wv*16 + col)*64 + pc]);
            #pragma unroll
            for (int t = 0; t < 4; t++){
                bf16x8 b = ldb8(&Wt[cb][(t*16 + col)*64 + pc]);
                acc[t] = MFMA16(a, b, acc[t]);
            }
        }
        __syncthreads();
    }

    float bfv[4];
    #pragma unroll
    for (int t = 0; t < 4; t++) bfv[t] = bias[n0 + t*16 + col];

    if constexpr (EPI == 3){
        __shared__ uint16_t Tsh[64*74];
        #pragma unroll
        for (int r = 0; r < 4; r++)
            #pragma unroll
            for (int t = 0; t < 4; t++)
                Tsh[(wv*16 + quad*4 + r)*74 + t*16 + col] = f2b(acc[t][r] + bfv[t]);
        __syncthreads();
        int e = tid & 63, sc = tid >> 6;       // ROUND 11: lane-major e
        int b = m0 >> 12;
        int sbat = m0 & (SN-1);
        int eb   = (n0 + e) >> 5;
        int l31e = (n0 + e) & 31;
        int k16  = (sbat >> 4) + sc;
        v8s p0, p1;
        #pragma unroll
        for (int i = 0; i < 8; i++) ((short*)&p0)[i] = (short)Tsh[(sc*16 + i)*74 + e];
        #pragma unroll
        for (int i = 0; i < 8; i++) ((short*)&p1)[i] = (short)Tsh[(sc*16 + 8 + i)*74 + e];
        bf16_t* dst = vt + ((((size_t)b*8 + eb)*256 + k16)*64 + l31e)*8;
        *(v8s*)dst = p0;              // half 0 (keys s&15 in 0..7)
        *(v8s*)(dst + 256) = p1;      // half 1 (keys s&15 in 8..15), +32 lanes
    } else {
        #pragma unroll
        for (int r = 0; r < 4; r++){
            int row = m0 + wv*16 + quad*4 + r;
            #pragma unroll
            for (int t = 0; t < 4; t++){
                float y = acc[t][r] + bfv[t];
                if constexpr (EPI == 1) y = fmaxf(y, 0.f);
                stsc(out + (size_t)row*N + n0 + t*16 + col, y);
            }
        }
    }
}

// ---------------------------------------------------------------------------
// ffn_ln: out = LN2( relu(x @ W1^T + b1) @ W2^T + b2 + x ) -> fp32.
// (Unchanged, verified round 10.)
// ---------------------------------------------------------------------------
__global__ __launch_bounds__(512) void ffn_ln_kernel(
    const bf16_t* __restrict__ x,  const bf16_t* __restrict__ W1b,
    const float* __restrict__ b1,  const bf16_t* __restrict__ W2b,
    const float* __restrict__ b2,  const float* __restrict__ gamma,
    const float* __restrict__ beta, float* __restrict__ out)
{
    __shared__ __align__(16) bf16_t W1c[2][16384];  // 2 x 32 KB [s][wr][p]
    __shared__ __align__(16) bf16_t W2c[2][16384];  // 2 x 32 KB [s2][wr2][p]
    __shared__ __align__(16) bf16_t Hs[64*68];      // 8.5 KB
    __shared__ float b1sh[1024];                    // 4 KB
    __shared__ float lnb[2][64][2];                 // 1 KB

    int tid  = threadIdx.x;
    int lane = tid & 63;
    int wv   = tid >> 6;         // 0..7
    int col  = lane & 15;
    int quad = lane >> 4;
    int mw   = wv >> 1;          // 0..3 -> rows mw*16..+16
    int nw   = wv & 1;           // 0..1
    int m0   = blockIdx.x * 64;

    b1sh[tid]       = b1[tid];
    b1sh[512 + tid] = b1[512 + tid];

    // x A-fragments in registers: row = m0 + mw*16 + col, k = kk*32+quad*8
    const bf16_t* xrow = x + (size_t)(m0 + mw*16 + col)*EN + quad*8;
    bf16x8 xr[8];
    #pragma unroll
    for (int kk = 0; kk < 8; kk++) xr[kk] = ldb8(xrow + kk*32);

    // epilogue constants: n = nw*128 + t2*16 + col
    float b2v[8], gv[8], bev[8];
    #pragma unroll
    for (int t2 = 0; t2 < 8; t2++){
        int nn = nw*128 + t2*16 + col;
        b2v[t2] = b2[nn]; gv[t2] = gamma[nn]; bev[t2] = beta[nn];
    }

    v4f acc[8];
    #pragma unroll
    for (int t2 = 0; t2 < 8; t2++) acc[t2] = (v4f){0.f,0.f,0.f,0.f};

    int wr  = tid >> 3;          // 0..63
    int pp  = tid & 7;
    int swz = (pp ^ (wr & 7)) * 8;

    // prologue: stage chunk 0 into parity 0 (8 glds16/thread)
    #pragma unroll
    for (int s = 0; s < 4; s++)
        glds16(W1b + (size_t)wr*256 + s*64 + swz, &W1c[0][s*4096 + tid*8]);
    #pragma unroll
    for (int s2 = 0; s2 < 4; s2++)
        glds16(W2b + (size_t)(s2*64 + wr)*1024 + swz, &W2c[0][s2*4096 + tid*8]);

    #pragma unroll 1
    for (int c = 0; c < 16; c++){
        int par = c & 1;
        if (c < 15){
            // stage chunk c+1 into parity^1 (stays in flight past the barrier)
            #pragma unroll
            for (int s = 0; s < 4; s++)
                glds16(W1b + (size_t)((c+1)*64 + wr)*256 + s*64 + swz,
                       &W1c[par^1][s*4096 + tid*8]);
            #pragma unroll
            for (int s2 = 0; s2 < 4; s2++)
                glds16(W2b + (size_t)(s2*64 + wr)*1024 + (c+1)*64 + swz,
                       &W2c[par^1][s2*4096 + tid*8]);
            asm volatile("s_waitcnt vmcnt(8)" ::: "memory");   // drain chunk c only
        } else {
            asm volatile("s_waitcnt vmcnt(0)" ::: "memory");
        }
        __builtin_amdgcn_s_barrier();
        __builtin_amdgcn_sched_barrier(0);

        // gemm1: h[64][64] = relu(x @ W1c^T + b1c); wave: rows mw*16, h-cols nw*32
        v4f hacc[2];
        hacc[0] = (v4f){0.f,0.f,0.f,0.f};
        hacc[1] = (v4f){0.f,0.f,0.f,0.f};
        #pragma unroll
        for (int kk = 0; kk < 8; kk++){
            #pragma unroll
            for (int t = 0; t < 2; t++){
                int hl = nw*32 + t*16 + col;
                bf16x8 b = ldb8(&W1c[par][(kk>>1)*4096 + hl*64
                                 + ((((kk&1)*4 + quad) ^ (hl & 7))*8)]);
                hacc[t] = MFMA16(xr[kk], b, hacc[t]);
            }
        }
        #pragma unroll
        for (int t = 0; t < 2; t++){
            float bb = b1sh[c*64 + nw*32 + t*16 + col];
            #pragma unroll
            for (int r = 0; r < 4; r++){
                float h = fmaxf(hacc[t][r] + bb, 0.f);
                Hs[(mw*16 + quad*4 + r)*68 + nw*32 + t*16 + col] = f2b(h);
            }
        }
        asm volatile("s_waitcnt lgkmcnt(0)" ::: "memory");
        __builtin_amdgcn_s_barrier();
        __builtin_amdgcn_sched_barrier(0);

        // gemm2: y2 += Hs @ W2c^T; wave: rows mw*16, n-cols nw*128
        #pragma unroll
        for (int kk2 = 0; kk2 < 2; kk2++){
            bf16x8 a2 = ldb8u(&Hs[(mw*16 + col)*68 + kk2*32 + quad*8]);
            #pragma unroll
            for (int t2 = 0; t2 < 8; t2++){
                int nn = nw*128 + t2*16 + col;
                bf16x8 bfr = ldb8(&W2c[par][(nn>>6)*4096 + (nn&63)*64
                                  + ((((kk2*4 + quad) ^ (col & 7)))*8)]);
                acc[t2] = MFMA16(a2, bfr, acc[t2]);
            }
        }
        asm volatile("s_waitcnt lgkmcnt(0)" ::: "memory");
        __builtin_amdgcn_s_barrier();   // all reads of par + Hs done
    }

    // ---- fused LN2 epilogue ----
    float v[8][4];
    float s1[4], s2[4];
    #pragma unroll
    for (int r = 0; r < 4; r++){ s1[r] = 0.f; s2[r] = 0.f; }
    #pragma unroll
    for (int r = 0; r < 4; r++){
        int row = m0 + mw*16 + quad*4 + r;
        #pragma unroll
        for (int t2 = 0; t2 < 8; t2++){
            int nn = nw*128 + t2*16 + col;
            float xv = acc[t2][r] + b2v[t2] + b2f(x[(size_t)row*EN + nn]);
            v[t2][r] = xv; s1[r] += xv; s2[r] += xv*xv;
        }
    }
    #pragma unroll
    for (int r = 0; r < 4; r++){
        #pragma unroll
        for (int m = 1; m <= 8; m <<= 1){
            s1[r] += __shfl_xor(s1[r], m);
            s2[r] += __shfl_xor(s2[r], m);
        }
    }
    if (col == 0){
        #pragma unroll
        for (int r = 0; r < 4; r++){
            int rl = mw*16 + quad*4 + r;
            lnb[nw][rl][0] = s1[r];
            lnb[nw][rl][1] = s2[r];
        }
    }
    __syncthreads();
    #pragma unroll
    for (int r = 0; r < 4; r++){
        int rl  = mw*16 + quad*4 + r;
        int row = m0 + rl;
        float S1 = lnb[0][rl][0] + lnb[1][rl][0];
        float S2 = lnb[0][rl][1] + lnb[1][rl][1];
        float mu = S1 * (1.f/256.f);
        float rs = rsqrtf(S2 * (1.f/256.f) - mu*mu + 1e-5f);
        #pragma unroll
        for (int t2 = 0; t2 < 8; t2++){
            int nn = nw*128 + t2*16 + col;
            out[(size_t)row*EN + nn] = (v[t2][r] - mu)*rs*gv[t2] + bev[t2];
        }
    }
}

// ---------------------------------------------------------------------------
// Attention round 19: main loop unchanged (chunk 256, raw barriers, parity
// dbuf). Epilogue: the 8 b0-set Wo-fragment loads hoisted ABOVE the den
// reduce + Osh store phase so their L2 latency hides under that work
// (+32 VGPR, stays under the 128 cliff).
// ---------------------------------------------------------------------------
__global__ __launch_bounds__(512, 2) void attn_kernel(
    const bf16_t* __restrict__ xk, const bf16_t* __restrict__ xq,
    const bf16_t* __restrict__ vf, const float* __restrict__ osp,
    const bf16_t* __restrict__ wof, const float* __restrict__ bo,
    const bf16_t* __restrict__ res, const float* __restrict__ gamma,
    const float* __restrict__ beta, bf16_t* __restrict__ out)
{
    __shared__ __align__(16) bf16_t Wtb[2][64*260];   // 65 KB
    __shared__ __align__(16) bf16_t Qs[64*64];        // 8 KB
    __shared__ __align__(16) bf16_t Osh[64*256];      // 32 KB (O tile, swizzled)
    __shared__ float densh[8][64];                    // 2 KB
    __shared__ float dent[64];
    __shared__ float lnw[8][64][2];                   // 4 KB

    int tid  = threadIdx.x;
    int lane = tid & 63;
    int wv   = tid >> 6;          // 0..7
    int col  = lane & 15;
    int quad = lane >> 4;
    int l31  = lane & 31;
    int half = lane >> 5;

    int bid = blockIdx.x;                    // 0..255
    int b   = (bid & 7) >> 1;
    int qi  = ((bid >> 3) << 1) | (bid & 1); // 0..63
    int q0  = qi * 64;

    float k2 = 1.4426950408889634f * osp[0];

    const bf16_t* xkb = xk + (size_t)b * SN * PAUG;
    const bf16_t* xqb = xq + (size_t)b * SN * PAUG;
    const bf16_t* vfb = vf + (((size_t)b*8 + wv)*256)*512 + lane*8;

    // stage Q tile: piece-swizzled SOURCE, linear dest
    {
        int qrow = tid >> 3;                 // 0..63
        int qpc  = (tid & 7) ^ (qrow & 7);
        glds16(xqb + (size_t)(q0 + qrow)*PAUG + qpc*8, &Qs[tid*8]);
    }

    v16f acc[2];
    #pragma unroll
    for (int qg = 0; qg < 2; qg++)
        #pragma unroll
        for (int i = 0; i < 16; i++) acc[qg][i] = 0.f;
    float den[4] = {0.f, 0.f, 0.f, 0.f};
    const v4f zero = (v4f){0.f,0.f,0.f,0.f};

    // kf prologue (chunk 0): this wave's 32 keys, 2 kg x 2 paug-halves
    bf16x8 kf[2][2];
    #pragma unroll
    for (int kg = 0; kg < 2; kg++)
        #pragma unroll
        for (int h = 0; h < 2; h++)
            kf[kg][h] = ldb8(xkb + (size_t)(wv*32 + kg*16 + col)*PAUG + h*32 + quad*8);

    __syncthreads();   // Qs staged

    for (int c = 0; c < 16; c++){
        int cb = c & 1;
        // issue V(c): 16 coalesced b128 into regs
        bf16x8 vr[16];
        #pragma unroll
        for (int sk = 0; sk < 16; sk++)
            vr[sk] = ldb8(vfb + (size_t)(c*16 + sk)*512);

        // QK + exp: this wave's 32-key slice x 64 q of chunk c
        #pragma unroll
        for (int qg = 0; qg < 2; qg++){
            #pragma unroll
            for (int g2 = 0; g2 < 2; g2++){
                int qr = qg*32 + g2*16 + col;
                bf16x8 qa = ldb8(&Qs[qr*64 + ((quad    ) ^ (col & 7))*8]);
                bf16x8 qb = ldb8(&Qs[qr*64 + ((4 + quad) ^ (col & 7))*8]);
                #pragma unroll
                for (int kg = 0; kg < 2; kg++){
                    v4f st = MFMA16(kf[kg][0], qa, zero);
                    st = MFMA16(kf[kg][1], qb, st);
                    #pragma unroll
                    for (int rp = 0; rp < 2; rp++){
                        float w0 = fexp2(fmaf(k2, fexp2(st[rp*2+0]), -k2));
                        float w1 = fexp2(fmaf(k2, fexp2(st[rp*2+1]), -k2));
                        den[qg*2+g2] += w0 + w1;
                        *(uint32_t*)&Wtb[cb][qr*260 + wv*32 + kg*16 + quad*4 + rp*2]
                            = pkbf16(w0, w1);
                    }
                }
            }
        }

        // prefetch kf(c+1) (stays in flight across raw barrier)
        if (c + 1 < 16){
            #pragma unroll
            for (int kg = 0; kg < 2; kg++)
                #pragma unroll
                for (int h = 0; h < 2; h++)
                    kf[kg][h] = ldb8(xkb + (size_t)((c+1)*256 + wv*32 + kg*16 + col)*PAUG
                                     + h*32 + quad*8);
        }

        asm volatile("s_waitcnt lgkmcnt(0)" ::: "memory");
        __builtin_amdgcn_s_barrier();
        __builtin_amdgcn_sched_barrier(0);

        // PV chunk c: this wave's 32-e slice, 2 qg x 16 MFMA32 over k=256
        #pragma unroll
        for (int qg = 0; qg < 2; qg++){
            #pragma unroll
            for (int sk4 = 0; sk4 < 4; sk4++){
                bf16x8 af[4];
                #pragma unroll
                for (int j = 0; j < 4; j++)
                    af[j] = ldb8u(&Wtb[cb][(qg*32 + l31)*260 + (sk4*4 + j)*16 + half*8]);
                #pragma unroll
                for (int j = 0; j < 4; j++)
                    acc[qg] = MFMA32(af[j], vr[sk4*4 + j], acc[qg]);
            }
        }
    }

    // ---- hoist Wo b0-set fragment loads (L2 latency hides under den+Osh) ----
    bf16x8 wf0[8];
    #pragma unroll
    for (int kc = 0; kc < 8; kc++)
        wf0[kc] = ldb8(wof + (size_t)(((wv*2+0)*8 + kc)*64 + lane)*8);

    // ---- den reduce ----
    #pragma unroll
    for (int d = 0; d < 4; d++){
        den[d] += __shfl_xor(den[d], 16);
        den[d] += __shfl_xor(den[d], 32);
    }
    if (lane < 16){
        #pragma unroll
        for (int qg = 0; qg < 2; qg++)
            #pragma unroll
            for (int g2 = 0; g2 < 2; g2++)
                densh[wv][qg*32 + g2*16 + lane] = den[qg*2+g2];
    }
    __syncthreads();
    if (tid < 64){
        float s = 0.f;
        #pragma unroll
        for (int w = 0; w < 8; w++) s += densh[w][tid];
        dent[tid] = 1.f / s;
    }
    __syncthreads();

    // ---- O -> LDS (write-side XOR piece swizzle) ----
    #pragma unroll
    for (int qg = 0; qg < 2; qg++){
        #pragma unroll
        for (int rg = 0; rg < 16; rg++){
            int qrow = qg*32 + (rg & 3) + 8*(rg >> 2) + 4*half;
            int e = wv*32 + l31;
            int g = e >> 3;
            Osh[qrow*256 + ((g ^ (qrow & 7))*8) + (e & 7)] = f2b(acc[qg][rg] * dent[qrow]);
        }
    }
    __syncthreads();

    // ---- y1 = O @ Wo^T : wave wv -> n-slice [wv*32, wv*32+32), K=256 ----
    v4f y[4][2];
    #pragma unroll
    for (int qg = 0; qg < 4; qg++)
        #pragma unroll
        for (int t = 0; t < 2; t++) y[qg][t] = (v4f){0.f,0.f,0.f,0.f};

    #pragma unroll
    for (int kc = 0; kc < 8; kc++){
        bf16x8 b1 = ldb8(wof + (size_t)(((wv*2+1)*8 + kc)*64 + lane)*8);
        #pragma unroll
        for (int qg = 0; qg < 4; qg++){
            bf16x8 a = ldb8(&Osh[(qg*16 + col)*256 + (((kc*4 + quad) ^ (col & 7))*8)]);
            y[qg][0] = MFMA16(a, wf0[kc], y[qg][0]);
            y[qg][1] = MFMA16(a, b1, y[qg][1]);
        }
    }

    // ---- bias + residual + LN1 partials ----
    size_t growb = (size_t)b*SN + q0;
    float bo0 = bo[wv*32 + col], bo1 = bo[wv*32 + 16 + col];
    #pragma unroll
    for (int qg = 0; qg < 4; qg++){
        #pragma unroll
        for (int r = 0; r < 4; r++){
            int row = qg*16 + quad*4 + r;
            float x0 = y[qg][0][r] + bo0 + b2f(res[(growb + row)*EN + wv*32 + col]);
            float x1 = y[qg][1][r] + bo1 + b2f(res[(growb + row)*EN + wv*32 + 16 + col]);
            y[qg][0][r] = x0; y[qg][1][r] = x1;
            float s1 = x0 + x1, s2 = x0*x0 + x1*x1;
            #pragma unroll
            for (int m = 1; m <= 8; m <<= 1){
                s1 += __shfl_xor(s1, m);
                s2 += __shfl_xor(s2, m);
            }
            if (col == 0){
                lnw[wv][row][0] = s1;
                lnw[wv][row][1] = s2;
            }
        }
    }
    __syncthreads();

    // ---- LN1 finalize + store ----
    float g0 = gamma[wv*32 + col],      g1v = gamma[wv*32 + 16 + col];
    float e0 = beta[wv*32 + col],       e1v = beta[wv*32 + 16 + col];
    #pragma unroll
    for (int qg = 0; qg < 4; qg++){
        #pragma unroll
        for (int r = 0; r < 4; r++){
            int row = qg*16 + quad*4 + r;
            float S1 = 0.f, S2 = 0.f;
            #pragma unroll
            for (int w = 0; w < 8; w++){ S1 += lnw[w][row][0]; S2 += lnw[w][row][1]; }
            float mu = S1 * (1.f/256.f);
            float rs = rsqrtf(S2 * (1.f/256.f) - mu*mu + 1e-5f);
            out[(growb + row)*EN + wv*32 + col]      = f2b((y[qg][0][r]-mu)*rs*g0 + e0);
            out[(growb + row)*EN + wv*32 + 16 + col] = f2b((y[qg][1][r]-mu)*rs*g1v + e1v);
        }
    }
}

// ---------------------------------------------------------------------------
extern "C" void kernel_launch(void* const* d_in, const int* in_sizes, int n_in,
                              void* d_out, int out_size, void* d_ws, size_t ws_size,
                              hipStream_t stream)
{
    (void)in_sizes; (void)n_in; (void)out_size; (void)ws_size;
    const float* src  = (const float*)d_in[0];
    const float* pos  = (const float*)d_in[1];
    const float* Wpos = (const float*)d_in[2];
    const float* bpos = (const float*)d_in[3];
    const float* ls   = (const float*)d_in[4];
    const float* os   = (const float*)d_in[5];
    const float* Wv   = (const float*)d_in[6];
    const float* bv   = (const float*)d_in[7];
    const float* Wo   = (const float*)d_in[8];
    const float* bo   = (const float*)d_in[9];
    const float* W1   = (const float*)d_in[10];
    const float* b1   = (const float*)d_in[11];
    const float* W2   = (const float*)d_in[12];
    const float* b2   = (const float*)d_in[13];
    const float* g1   = (const float*)d_in[14];
    const float* be1  = (const float*)d_in[15];
    const float* g2   = (const float*)d_in[16];
    const float* be2  = (const float*)d_in[17];

    char* w = (char*)d_ws;
    bf16_t* xkb  = (bf16_t*)(w);                         // 2 MB [B,S,64]
    bf16_t* xqb  = (bf16_t*)(w + ( 2u<<20));             // 2 MB
    bf16_t* Wvb  = (bf16_t*)(w + ( 4u<<20));             // 128 KB
    bf16_t* Wob  = (bf16_t*)(w + ( 4u<<20) + (1u<<18));  // 128 KB (fragment order)
    bf16_t* W1b  = (bf16_t*)(w + ( 5u<<20));             // 512 KB
    bf16_t* W2b  = (bf16_t*)(w + ( 6u<<20));             // 512 KB
    bf16_t* srcb = (bf16_t*)(w + ( 8u<<20));             // 8 MB (alive thru attn res)
    bf16_t* vtg  = (bf16_t*)(w + (16u<<20));             // 8 MB vfrag
    bf16_t* xws  = (bf16_t*)(w + (24u<<20));             // 8 MB (x = LN1 out)

    prep_kernel<<<dim3(4800), 256, 0, stream>>>(
        src, srcb, Wv, Wvb, Wo, Wob, W1, W1b, W2, W2b,
        pos, Wpos, bpos, ls, xkb, xqb);

    // v = src @ Wv^T + bv  -> fragment-ordered store vfrag[b][eb][k16][lane][8]
    gemm_t<3, bf16_t><<<dim3(BS/64, EN/64), 256, 0, stream>>>(
        srcb, Wvb, bv, (bf16_t*)nullptr, vtg, EN, EN);
    // x = LN1( softmax(..) @ v @ Wo^T + bo + src )   [attn + Wo + LN1 fused]
    attn_kernel<<<dim3(256), 512, 0, stream>>>(
        xkb, xqb, vtg, os, Wob, bo, srcb, g1, be1, xws);
    // out = LN2( relu(x@W1^T+b1) @ W2^T + b2 + x )   [FFN + LN2 fused]
    ffn_ln_kernel<<<dim3(BS/64), 512, 0, stream>>>(
        xws, W1b, b1, W2b, b2, g2, be2, (float*)d_out);
}